// Round 5
// baseline (744.555 us; speedup 1.0000x reference)
//
#include <hip/hip_runtime.h>
#include <stdint.h>

// ---------------------------------------------------------------------------
// GCastHeterocoder round 5: CSR two-phase aggregation (no scatter atomics).
//  edge MLP writes P rows (bf16, sequential) + edge_out; CSR built on device
//  (hist -> 2-level scan -> scatter); agg kernel gather-sums P per receiver.
//  Epilogue LDS transpose in bf16 (halves LDS). Tiered fallback to atomics.
// ---------------------------------------------------------------------------

typedef __bf16 bf16x8 __attribute__((ext_vector_type(8)));
typedef float  f32x4  __attribute__((ext_vector_type(4)));

union U16B { uint4 u; bf16x8 v; };
union BFPK { __bf16 h[2]; unsigned int u; };
union BF1  { __bf16 h; unsigned short s; };

__device__ __forceinline__ float silu_f(float x) {
  return x * __builtin_amdgcn_rcpf(1.0f + __expf(-x));
}
__device__ __forceinline__ float bfu2f(unsigned int lo16) {
  return __uint_as_float(lo16 << 16);
}
__device__ __forceinline__ bf16x8 cvt8(float4 a, float4 b) {
  bf16x8 r;
  r[0] = (__bf16)a.x; r[1] = (__bf16)a.y; r[2] = (__bf16)a.z; r[3] = (__bf16)a.w;
  r[4] = (__bf16)b.x; r[5] = (__bf16)b.y; r[6] = (__bf16)b.z; r[7] = (__bf16)b.w;
  return r;
}

// ---------------- weight / feature conversion ----------------
__global__ void cvt_weights_kernel(const float* __restrict__ We,
                                   const float* __restrict__ Wn,
                                   const float* __restrict__ Ws,
                                   unsigned short* __restrict__ out) {
  const int nWe = 128 * 384, nWn = 128 * 256, nWs = 128 * 128;
  int i = blockIdx.x * 256 + threadIdx.x;
  float f;
  if (i < nWe) f = We[i];
  else if (i < nWe + nWn) f = Wn[i - nWe];
  else if (i < nWe + nWn + nWs) f = Ws[i - nWe - nWn];
  else return;
  BF1 c; c.h = (__bf16)f;
  out[i] = c.s;
}

__global__ void cvt_rows_kernel(const float* __restrict__ in,
                                unsigned short* __restrict__ out, int n8) {
  int i = blockIdx.x * 256 + threadIdx.x;
  if (i >= n8) return;
  float4 a = reinterpret_cast<const float4*>(in)[2 * i];
  float4 b = reinterpret_cast<const float4*>(in)[2 * i + 1];
  U16B r; r.v = cvt8(a, b);
  reinterpret_cast<uint4*>(out)[i] = r.u;
}

// ---------------- CSR build ----------------
__global__ void hist_kernel(const int* __restrict__ dst, int* __restrict__ counts, int E) {
  int i = blockIdx.x * 256 + threadIdx.x;
  if (i < E) atomicAdd(&counts[dst[i]], 1);
}

// per-block (1024 elems) exclusive scan; writes per-elem excl prefix + block sum
__global__ void scan1_kernel(const int* __restrict__ counts, int* __restrict__ pre,
                             int* __restrict__ blockSums, int n) {
  __shared__ int sh[256];
  const int t = threadIdx.x;
  const int base = blockIdx.x * 1024 + t * 4;
  int c0 = (base + 0 < n) ? counts[base + 0] : 0;
  int c1 = (base + 1 < n) ? counts[base + 1] : 0;
  int c2 = (base + 2 < n) ? counts[base + 2] : 0;
  int c3 = (base + 3 < n) ? counts[base + 3] : 0;
  int tot = c0 + c1 + c2 + c3;
  sh[t] = tot;
  __syncthreads();
  #pragma unroll
  for (int off = 1; off < 256; off <<= 1) {
    int v = (t >= off) ? sh[t - off] : 0;
    __syncthreads();
    sh[t] += v;
    __syncthreads();
  }
  int excl = sh[t] - tot;  // exclusive prefix of this thread's 4 elems
  if (base + 0 < n) pre[base + 0] = excl;
  if (base + 1 < n) pre[base + 1] = excl + c0;
  if (base + 2 < n) pre[base + 2] = excl + c0 + c1;
  if (base + 3 < n) pre[base + 3] = excl + c0 + c1 + c2;
  if (t == 255) blockSums[blockIdx.x] = sh[255];
}

// single-block exclusive scan of up to 512 block sums (in place)
__global__ void scan2_kernel(int* __restrict__ blockSums, int nb) {
  __shared__ int sh[512];
  const int t = threadIdx.x;
  int v = (t < nb) ? blockSums[t] : 0;
  sh[t] = v;
  __syncthreads();
  #pragma unroll
  for (int off = 1; off < 512; off <<= 1) {
    int u = (t >= off) ? sh[t - off] : 0;
    __syncthreads();
    sh[t] += u;
    __syncthreads();
  }
  if (t < nb) blockSums[t] = sh[t] - v;  // exclusive
}

// add block offsets -> final exclusive offsets; also init cursor copy
__global__ void scan3_kernel(const int* __restrict__ pre, const int* __restrict__ blockSums,
                             int* __restrict__ offs, int* __restrict__ cursor, int n) {
  int i = blockIdx.x * 256 + threadIdx.x;
  if (i >= n) return;
  int o = pre[i] + blockSums[i >> 10];
  offs[i] = o;
  cursor[i] = o;
}

__global__ void scatter_kernel(const int* __restrict__ dst, int* __restrict__ cursor,
                               int* __restrict__ eorder, int E) {
  int i = blockIdx.x * 256 + threadIdx.x;
  if (i < E) {
    int p = atomicAdd(&cursor[dst[i]], 1);
    eorder[p] = i;
  }
}

// ---------------- segment gather-sum: aggr[r] = sum P[e in CSR(r)] ----------------
__global__ __launch_bounds__(256) void agg_kernel(
    const unsigned short* __restrict__ P, const int* __restrict__ eorder,
    const int* __restrict__ offs, const int* __restrict__ counts,
    unsigned short* __restrict__ aggr, int NR) {
  const int l = threadIdx.x & 31;                       // lane in 32-group: 4 ch
  const int g0 = (blockIdx.x * 256 + threadIdx.x) >> 5; // global group id
  const int ngroups = (gridDim.x * 256) >> 5;
  for (int r = g0; r < NR; r += ngroups) {
    int beg = offs[r];
    int cnt = counts[r];
    float s0 = 0.f, s1 = 0.f, s2 = 0.f, s3 = 0.f;
    for (int k = 0; k < cnt; ++k) {
      int e = eorder[beg + k];
      uint2 w = *reinterpret_cast<const uint2*>(P + (size_t)e * 128 + l * 4);
      s0 += bfu2f(w.x & 0xffffu);
      s1 += bfu2f(w.x >> 16);
      s2 += bfu2f(w.y & 0xffffu);
      s3 += bfu2f(w.y >> 16);
    }
    BFPK a, b;
    a.h[0] = (__bf16)s0; a.h[1] = (__bf16)s1;
    b.h[0] = (__bf16)s2; b.h[1] = (__bf16)s3;
    uint2 o; o.x = a.u; o.y = b.u;
    *reinterpret_cast<uint2*>(aggr + (size_t)r * 128 + l * 4) = o;
  }
}

// ---------------------------------------------------------------------------
// Fused GCastMLP. AGGR: 0=none, 1=fp32 atomicAdd, 2=pk bf16 atomics,
// 3=write P rows (bf16) to `aggr` (CSR mode). S0B/S1B: segment dtype bf16.
// 256 thr / 4 waves, 128 rows per block, wave owns 32 rows x 128 ch.
// ---------------------------------------------------------------------------
template <int KDIM, int AGGR, bool S0B, bool S1B>
__global__ __launch_bounds__(256, 4) void mlp_rf2_kernel(
    const void* __restrict__ s0v, const int* __restrict__ i0,
    const void* __restrict__ s1v, const int* __restrict__ i1,
    const float* __restrict__ s2,
    const unsigned short* __restrict__ Wb,   // [128][KDIM] bf16 row-major
    const float* __restrict__ bias, const float* __restrict__ gamma,
    const float* __restrict__ beta,
    const float* __restrict__ resid,
    float* __restrict__ outp,
    void* aggr, const int* __restrict__ aggr_idx,
    int M) {
  __shared__ __align__(16) unsigned short yT[4][16][132];  // bf16 transpose, 16.9 KB

  const int tid = threadIdx.x;
  const int wid = tid >> 6;
  const int lane = tid & 63;
  const int l15 = lane & 15;
  const int q = lane >> 4;
  const int l31 = lane & 31;
  const int rhalf = lane >> 5;
  const int wrow0 = blockIdx.x * 128 + wid * 32;

  const unsigned short* p0b[2]; const float* p0f[2];
  const unsigned short* p1b[2]; const float* p1f[2];
  const float* p2[2];
  #pragma unroll
  for (int mt = 0; mt < 2; ++mt) {
    int r = wrow0 + mt * 16 + l15;
    if (r >= M) r = M - 1;  // clamp tail; stores masked later
    int r0 = i0 ? i0[r] : r;
    if constexpr (S0B) p0b[mt] = (const unsigned short*)s0v + (size_t)r0 * 128;
    else               p0f[mt] = (const float*)s0v + (size_t)r0 * 128;
    if constexpr (KDIM >= 256) {
      int r1 = i1 ? i1[r] : r;
      if constexpr (S1B) p1b[mt] = (const unsigned short*)s1v + (size_t)r1 * 128;
      else               p1f[mt] = (const float*)s1v + (size_t)r1 * 128;
    }
    if constexpr (KDIM >= 384) p2[mt] = s2 + (size_t)r * 128;
  }

  f32x4 acc[2][8] = {};

  #pragma unroll
  for (int ks = 0; ks < KDIM / 32; ++ks) {
    const int seg = ks >> 2;
    const int kof = (ks & 3) * 32 + q * 8;
    U16B a[2];
    #pragma unroll
    for (int mt = 0; mt < 2; ++mt) {
      if (seg == 0) {
        if constexpr (S0B) {
          a[mt].u = *reinterpret_cast<const uint4*>(p0b[mt] + kof);
        } else {
          const float4* p = reinterpret_cast<const float4*>(p0f[mt] + kof);
          a[mt].v = cvt8(p[0], p[1]);
        }
      } else if (seg == 1) {
        if constexpr (S1B) {
          a[mt].u = *reinterpret_cast<const uint4*>(p1b[mt] + kof);
        } else {
          const float4* p = reinterpret_cast<const float4*>(p1f[mt] + kof);
          a[mt].v = cvt8(p[0], p[1]);
        }
      } else {
        const float4* p = reinterpret_cast<const float4*>(p2[mt] + kof);
        a[mt].v = cvt8(p[0], p[1]);
      }
    }
    #pragma unroll
    for (int n = 0; n < 8; ++n) {
      U16B b;
      b.u = *reinterpret_cast<const uint4*>(Wb + (size_t)(n * 16 + l15) * KDIM + ks * 32 + q * 8);
      acc[0][n] = __builtin_amdgcn_mfma_f32_16x16x32_bf16(a[0].v, b.v, acc[0][n], 0, 0, 0);
      acc[1][n] = __builtin_amdgcn_mfma_f32_16x16x32_bf16(a[1].v, b.v, acc[1][n], 0, 0, 0);
    }
  }

  // ---- epilogue ----
  float bia[8], gam[8], bet[8];
  #pragma unroll
  for (int n = 0; n < 8; ++n) {
    int ch = n * 16 + l15;
    bia[n] = bias[ch]; gam[n] = gamma[ch]; bet[n] = beta[ch];
  }

  #pragma unroll
  for (int mt = 0; mt < 2; ++mt) {
    float vv[8][4];
    float sum[4] = {0.f, 0.f, 0.f, 0.f};
    float ssq[4] = {0.f, 0.f, 0.f, 0.f};
    #pragma unroll
    for (int n = 0; n < 8; ++n) {
      #pragma unroll
      for (int j = 0; j < 4; ++j) {
        float t = silu_f(silu_f(acc[mt][n][j] + bia[n]));
        vv[n][j] = t;
        sum[j] += t;
        ssq[j] += t * t;
      }
    }
    #pragma unroll
    for (int off = 1; off < 16; off <<= 1) {
      #pragma unroll
      for (int j = 0; j < 4; ++j) {
        sum[j] += __shfl_xor(sum[j], off);
        ssq[j] += __shfl_xor(ssq[j], off);
      }
    }
    float mu[4], rs[4];
    #pragma unroll
    for (int j = 0; j < 4; ++j) {
      mu[j] = sum[j] * (1.0f / 128.0f);
      float var = ssq[j] * (1.0f / 128.0f) - mu[j] * mu[j];
      rs[j] = rsqrtf(var + 1e-5f);
    }

    if (mt == 1) {  // WAR guard: mt0 reads must complete before overwrite
      asm volatile("s_waitcnt lgkmcnt(0)" ::: "memory");
    }
    // transpose through LDS (bf16): y[row16 = q*4+j][ch = n*16+l15]
    #pragma unroll
    for (int n = 0; n < 8; ++n) {
      #pragma unroll
      for (int j = 0; j < 4; ++j) {
        float y = (vv[n][j] - mu[j]) * rs[j] * gam[n] + bet[n];
        BF1 c; c.h = (__bf16)y;
        yT[wid][q * 4 + j][n * 16 + l15] = c.s;
      }
    }
    asm volatile("s_waitcnt lgkmcnt(0)" ::: "memory");

    // coalesced store phase: 2 rows per pass, lane -> 4 contiguous channels
    #pragma unroll
    for (int s = 0; s < 8; ++s) {
      int row16 = 2 * s + rhalf;
      int grow = wrow0 + mt * 16 + row16;
      uint2 w = *reinterpret_cast<const uint2*>(&yT[wid][row16][l31 * 4]);
      if (grow < M) {
        const f32x4 r4 = *reinterpret_cast<const f32x4*>(resid + (size_t)grow * 128 + l31 * 4);
        f32x4 o4;
        o4.x = r4.x + bfu2f(w.x & 0xffffu);
        o4.y = r4.y + bfu2f(w.x >> 16);
        o4.z = r4.z + bfu2f(w.y & 0xffffu);
        o4.w = r4.w + bfu2f(w.y >> 16);
        __builtin_nontemporal_store(o4, reinterpret_cast<f32x4*>(outp + (size_t)grow * 128 + l31 * 4));
        if constexpr (AGGR == 3) {
          *reinterpret_cast<uint2*>((unsigned short*)aggr + (size_t)grow * 128 + l31 * 4) = w;
        } else if constexpr (AGGR == 2) {
          int idx = aggr_idx[grow];
          unsigned short* ar = (unsigned short*)aggr + (size_t)idx * 128 + l31 * 4;
          asm volatile("global_atomic_pk_add_bf16 %0, %1, off" :: "v"(ar), "v"(w.x) : "memory");
          asm volatile("global_atomic_pk_add_bf16 %0, %1, off" :: "v"(ar + 2), "v"(w.y) : "memory");
        } else if constexpr (AGGR == 1) {
          int idx = aggr_idx[grow];
          float* ar = (float*)aggr + (size_t)idx * 128 + l31 * 4;
          atomicAdd(ar + 0, bfu2f(w.x & 0xffffu));
          atomicAdd(ar + 1, bfu2f(w.x >> 16));
          atomicAdd(ar + 2, bfu2f(w.y & 0xffffu));
          atomicAdd(ar + 3, bfu2f(w.y >> 16));
        }
      }
    }
  }
}

extern "C" void kernel_launch(void* const* d_in, const int* in_sizes, int n_in,
                              void* d_out, int out_size, void* d_ws, size_t ws_size,
                              hipStream_t stream) {
  const float* sender_x   = (const float*)d_in[0];
  const float* receiver_x = (const float*)d_in[1];
  const int*   edge_index = (const int*)d_in[2];
  const float* edge_attr  = (const float*)d_in[3];
  const float* We  = (const float*)d_in[4];
  const float* be  = (const float*)d_in[5];
  const float* ge  = (const float*)d_in[6];
  const float* bbe = (const float*)d_in[7];
  const float* Wn  = (const float*)d_in[8];
  const float* bn  = (const float*)d_in[9];
  const float* gn  = (const float*)d_in[10];
  const float* bbn = (const float*)d_in[11];
  const float* Ws  = (const float*)d_in[12];
  const float* bs  = (const float*)d_in[13];
  const float* gs  = (const float*)d_in[14];
  const float* bbs = (const float*)d_in[15];

  const int D  = 128;
  const int NS = in_sizes[0] / D;
  const int NR = in_sizes[1] / D;
  const int E  = in_sizes[2] / 2;

  const int* src = edge_index;
  const int* dst = edge_index + E;

  float* out          = (float*)d_out;
  float* sender_out   = out;
  float* receiver_out = out + (size_t)NS * D;
  float* edge_out     = out + (size_t)(NS + NR) * D;

  // ---- ws layout (ushort units unless noted) ----
  const size_t welems = 128 * 384 + 128 * 256 + 128 * 128;   // 98304
  unsigned short* We_b = (unsigned short*)d_ws;
  unsigned short* Wn_b = We_b + 128 * 384;
  unsigned short* Ws_b = Wn_b + 128 * 256;
  unsigned short* sender_b   = We_b + welems;
  unsigned short* receiver_b = sender_b + (size_t)NS * D;
  unsigned short* aggr_b     = receiver_b + (size_t)NR * D;
  unsigned short* P_b        = aggr_b + (size_t)NR * D;
  int* counts    = (int*)(P_b + (size_t)E * D);
  int* pre       = counts + NR;
  int* offs      = pre + NR;
  int* cursor    = offs + NR;
  int* blockSums = cursor + NR;
  int* eorder    = blockSums + 512;

  const int nScanBlocks = (NR + 1023) / 1024;
  const size_t needCSR = 2 * (welems + (size_t)(NS + 2 * NR) * D + (size_t)E * D)
                       + 4 * (4 * (size_t)NR + 512 + (size_t)E);
  const size_t needA = (welems + (size_t)(NS + 2 * NR) * D) * 2;
  const size_t needB = (welems + (size_t)NR * D) * 2;
  unsigned short* aggrB = We_b + welems;  // tier-2 layout: aggr right after weights

  int tier;
  if (ws_size >= needCSR && nScanBlocks <= 512) tier = 0;
  else if (ws_size >= needA) tier = 1;
  else if (ws_size >= needB) tier = 2;
  else tier = 3;

  cvt_weights_kernel<<<(int)((welems + 255) / 256), 256, 0, stream>>>(We, Wn, Ws, We_b);

  const int gridE = (E + 127) / 128;
  const int gridR = (NR + 127) / 128;
  const int gridS = (NS + 127) / 128;
  const int n8s = NS * D / 8, n8r = NR * D / 8;

  if (tier == 0) {
    cvt_rows_kernel<<<(n8s + 255) / 256, 256, 0, stream>>>(sender_x, sender_b, n8s);
    cvt_rows_kernel<<<(n8r + 255) / 256, 256, 0, stream>>>(receiver_x, receiver_b, n8r);

    // CSR build
    (void)hipMemsetAsync(counts, 0, (size_t)NR * 4, stream);
    hist_kernel<<<(E + 255) / 256, 256, 0, stream>>>(dst, counts, E);
    scan1_kernel<<<nScanBlocks, 256, 0, stream>>>(counts, pre, blockSums, NR);
    scan2_kernel<<<1, 512, 0, stream>>>(blockSums, nScanBlocks);
    scan3_kernel<<<(NR + 255) / 256, 256, 0, stream>>>(pre, blockSums, offs, cursor, NR);
    scatter_kernel<<<(E + 255) / 256, 256, 0, stream>>>(dst, cursor, eorder, E);

    // 1) Edge MLP: writes edge_out + P rows (bf16)
    mlp_rf2_kernel<384, 3, true, true><<<gridE, 256, 0, stream>>>(
        sender_b, src, receiver_b, dst, edge_attr,
        We_b, be, ge, bbe, edge_attr, edge_out, P_b, nullptr, E);

    // 2) segment gather-sum
    agg_kernel<<<(NR + 7) / 8, 256, 0, stream>>>(P_b, eorder, offs, counts, aggr_b, NR);

    // 3) Node MLP
    mlp_rf2_kernel<256, 0, true, true><<<gridR, 256, 0, stream>>>(
        receiver_b, nullptr, aggr_b, nullptr, nullptr,
        Wn_b, bn, gn, bbn, receiver_x, receiver_out, nullptr, nullptr, NR);

    // 4) Sender MLP
    mlp_rf2_kernel<128, 0, true, false><<<gridS, 256, 0, stream>>>(
        sender_b, nullptr, nullptr, nullptr, nullptr,
        Ws_b, bs, gs, bbs, sender_x, sender_out, nullptr, nullptr, NS);
  } else if (tier == 1) {
    cvt_rows_kernel<<<(n8s + 255) / 256, 256, 0, stream>>>(sender_x, sender_b, n8s);
    cvt_rows_kernel<<<(n8r + 255) / 256, 256, 0, stream>>>(receiver_x, receiver_b, n8r);
    (void)hipMemsetAsync(aggr_b, 0, (size_t)NR * D * 2, stream);

    mlp_rf2_kernel<384, 2, true, true><<<gridE, 256, 0, stream>>>(
        sender_b, src, receiver_b, dst, edge_attr,
        We_b, be, ge, bbe, edge_attr, edge_out, aggr_b, dst, E);

    mlp_rf2_kernel<256, 0, true, true><<<gridR, 256, 0, stream>>>(
        receiver_b, nullptr, aggr_b, nullptr, nullptr,
        Wn_b, bn, gn, bbn, receiver_x, receiver_out, nullptr, nullptr, NR);

    mlp_rf2_kernel<128, 0, true, false><<<gridS, 256, 0, stream>>>(
        sender_b, nullptr, nullptr, nullptr, nullptr,
        Ws_b, bs, gs, bbs, sender_x, sender_out, nullptr, nullptr, NS);
  } else if (tier == 2) {
    (void)hipMemsetAsync(aggrB, 0, (size_t)NR * D * 2, stream);

    mlp_rf2_kernel<384, 2, false, false><<<gridE, 256, 0, stream>>>(
        sender_x, src, receiver_x, dst, edge_attr,
        We_b, be, ge, bbe, edge_attr, edge_out, aggrB, dst, E);

    mlp_rf2_kernel<256, 0, false, true><<<gridR, 256, 0, stream>>>(
        receiver_x, nullptr, aggrB, nullptr, nullptr,
        Wn_b, bn, gn, bbn, receiver_x, receiver_out, nullptr, nullptr, NR);

    mlp_rf2_kernel<128, 0, false, false><<<gridS, 256, 0, stream>>>(
        sender_x, nullptr, nullptr, nullptr, nullptr,
        Ws_b, bs, gs, bbs, sender_x, sender_out, nullptr, nullptr, NS);
  } else {
    (void)hipMemsetAsync(receiver_out, 0, (size_t)NR * D * sizeof(float), stream);

    mlp_rf2_kernel<384, 1, false, false><<<gridE, 256, 0, stream>>>(
        sender_x, src, receiver_x, dst, edge_attr,
        We_b, be, ge, bbe, edge_attr, edge_out, receiver_out, dst, E);

    mlp_rf2_kernel<256, 0, false, false><<<gridR, 256, 0, stream>>>(
        receiver_x, nullptr, receiver_out, nullptr, nullptr,
        Wn_b, bn, gn, bbn, receiver_x, receiver_out, nullptr, nullptr, NR);

    mlp_rf2_kernel<128, 0, false, false><<<gridS, 256, 0, stream>>>(
        sender_x, nullptr, nullptr, nullptr, nullptr,
        Ws_b, bs, gs, bbs, sender_x, sender_out, nullptr, nullptr, NS);
  }
}

// Round 6
// 665.044 us; speedup vs baseline: 1.1196x; 1.1196x over previous
//
#include <hip/hip_runtime.h>
#include <stdint.h>

// ---------------------------------------------------------------------------
// GCastHeterocoder round 6: register-fragment MFMA MLP with per-segment
// A-prefetch (one gather-latency exposure per 128-col segment instead of 4),
// launch_bounds(256,3) for reg headroom, CSR aggregation with rank-remapped
// sequential P (edge kernel scatters P rows to sorted positions; agg kernel
// streams P contiguously per receiver).
// ---------------------------------------------------------------------------

typedef __bf16 bf16x8 __attribute__((ext_vector_type(8)));
typedef float  f32x4  __attribute__((ext_vector_type(4)));

union U16B { uint4 u; bf16x8 v; };
union BFPK { __bf16 h[2]; unsigned int u; };
union BF1  { __bf16 h; unsigned short s; };

__device__ __forceinline__ float silu_f(float x) {
  return x * __builtin_amdgcn_rcpf(1.0f + __expf(-x));
}
__device__ __forceinline__ float bfu2f(unsigned int lo16) {
  return __uint_as_float(lo16 << 16);
}
__device__ __forceinline__ bf16x8 cvt8(float4 a, float4 b) {
  bf16x8 r;
  r[0] = (__bf16)a.x; r[1] = (__bf16)a.y; r[2] = (__bf16)a.z; r[3] = (__bf16)a.w;
  r[4] = (__bf16)b.x; r[5] = (__bf16)b.y; r[6] = (__bf16)b.z; r[7] = (__bf16)b.w;
  return r;
}

// ---------------- weight / feature conversion ----------------
__global__ void cvt_weights_kernel(const float* __restrict__ We,
                                   const float* __restrict__ Wn,
                                   const float* __restrict__ Ws,
                                   unsigned short* __restrict__ out) {
  const int nWe = 128 * 384, nWn = 128 * 256, nWs = 128 * 128;
  int i = blockIdx.x * 256 + threadIdx.x;
  float f;
  if (i < nWe) f = We[i];
  else if (i < nWe + nWn) f = Wn[i - nWe];
  else if (i < nWe + nWn + nWs) f = Ws[i - nWe - nWn];
  else return;
  BF1 c; c.h = (__bf16)f;
  out[i] = c.s;
}

__global__ void cvt_rows_kernel(const float* __restrict__ in,
                                unsigned short* __restrict__ out, int n8) {
  int i = blockIdx.x * 256 + threadIdx.x;
  if (i >= n8) return;
  float4 a = reinterpret_cast<const float4*>(in)[2 * i];
  float4 b = reinterpret_cast<const float4*>(in)[2 * i + 1];
  U16B r; r.v = cvt8(a, b);
  reinterpret_cast<uint4*>(out)[i] = r.u;
}

// ---------------- CSR build ----------------
__global__ void hist_kernel(const int* __restrict__ dst, int* __restrict__ counts, int E) {
  int i = blockIdx.x * 256 + threadIdx.x;
  if (i < E) atomicAdd(&counts[dst[i]], 1);
}

__global__ void scan1_kernel(const int* __restrict__ counts, int* __restrict__ pre,
                             int* __restrict__ blockSums, int n) {
  __shared__ int sh[256];
  const int t = threadIdx.x;
  const int base = blockIdx.x * 1024 + t * 4;
  int c0 = (base + 0 < n) ? counts[base + 0] : 0;
  int c1 = (base + 1 < n) ? counts[base + 1] : 0;
  int c2 = (base + 2 < n) ? counts[base + 2] : 0;
  int c3 = (base + 3 < n) ? counts[base + 3] : 0;
  int tot = c0 + c1 + c2 + c3;
  sh[t] = tot;
  __syncthreads();
  #pragma unroll
  for (int off = 1; off < 256; off <<= 1) {
    int v = (t >= off) ? sh[t - off] : 0;
    __syncthreads();
    sh[t] += v;
    __syncthreads();
  }
  int excl = sh[t] - tot;
  if (base + 0 < n) pre[base + 0] = excl;
  if (base + 1 < n) pre[base + 1] = excl + c0;
  if (base + 2 < n) pre[base + 2] = excl + c0 + c1;
  if (base + 3 < n) pre[base + 3] = excl + c0 + c1 + c2;
  if (t == 255) blockSums[blockIdx.x] = sh[255];
}

__global__ void scan2_kernel(int* __restrict__ blockSums, int nb) {
  __shared__ int sh[512];
  const int t = threadIdx.x;
  int v = (t < nb) ? blockSums[t] : 0;
  sh[t] = v;
  __syncthreads();
  #pragma unroll
  for (int off = 1; off < 512; off <<= 1) {
    int u = (t >= off) ? sh[t - off] : 0;
    __syncthreads();
    sh[t] += u;
    __syncthreads();
  }
  if (t < nb) blockSums[t] = sh[t] - v;
}

__global__ void scan3_kernel(const int* __restrict__ pre, const int* __restrict__ blockSums,
                             int* __restrict__ offs, int* __restrict__ cursor, int n) {
  int i = blockIdx.x * 256 + threadIdx.x;
  if (i >= n) return;
  int o = pre[i] + blockSums[i >> 10];
  offs[i] = o;
  cursor[i] = o;
}

// rank[e] = sorted position of edge e (dst-sorted); P written there -> agg streams
__global__ void scatter_kernel(const int* __restrict__ dst, int* __restrict__ cursor,
                               int* __restrict__ rank, int E) {
  int i = blockIdx.x * 256 + threadIdx.x;
  if (i < E) {
    int p = atomicAdd(&cursor[dst[i]], 1);
    rank[i] = p;
  }
}

// segment sum over CONTIGUOUS P rows [offs[r], offs[r]+counts[r])
__global__ __launch_bounds__(256) void agg_kernel(
    const unsigned short* __restrict__ P,
    const int* __restrict__ offs, const int* __restrict__ counts,
    unsigned short* __restrict__ aggr, int NR) {
  const int l = threadIdx.x & 31;
  const int g0 = (blockIdx.x * 256 + threadIdx.x) >> 5;
  if (g0 >= NR) return;
  int beg = offs[g0];
  int cnt = counts[g0];
  float s0 = 0.f, s1 = 0.f, s2 = 0.f, s3 = 0.f;
  const unsigned short* p = P + (size_t)beg * 128 + l * 4;
  for (int k = 0; k < cnt; ++k) {
    uint2 w = *reinterpret_cast<const uint2*>(p);
    p += 128;
    s0 += bfu2f(w.x & 0xffffu);
    s1 += bfu2f(w.x >> 16);
    s2 += bfu2f(w.y & 0xffffu);
    s3 += bfu2f(w.y >> 16);
  }
  BFPK a, b;
  a.h[0] = (__bf16)s0; a.h[1] = (__bf16)s1;
  b.h[0] = (__bf16)s2; b.h[1] = (__bf16)s3;
  uint2 o; o.x = a.u; o.y = b.u;
  *reinterpret_cast<uint2*>(aggr + (size_t)g0 * 128 + l * 4) = o;
}

// ---------------------------------------------------------------------------
// Fused GCastMLP. AGGR: 0=none, 1=fp32 atomicAdd, 2=pk bf16 atomics,
// 3=write P row (bf16) at prank[grow]. S0B/S1B: segment dtype bf16.
// 256 thr / 4 waves, 128 rows/block, wave owns 32 rows x 128 ch.
// Per-128-col-segment A prefetch: one gather-latency exposure per segment.
// ---------------------------------------------------------------------------
template <int KDIM, int AGGR, bool S0B, bool S1B>
__global__ __launch_bounds__(256, 3) void mlp_rf3_kernel(
    const void* __restrict__ s0v, const int* __restrict__ i0,
    const void* __restrict__ s1v, const int* __restrict__ i1,
    const float* __restrict__ s2,
    const unsigned short* __restrict__ Wb,
    const float* __restrict__ bias, const float* __restrict__ gamma,
    const float* __restrict__ beta,
    const float* __restrict__ resid,
    float* __restrict__ outp,
    void* aggr, const int* __restrict__ aggr_idx,
    const int* __restrict__ prank,
    int M) {
  __shared__ __align__(16) unsigned short yT[4][16][132];

  const int tid = threadIdx.x;
  const int wid = tid >> 6;
  const int lane = tid & 63;
  const int l15 = lane & 15;
  const int q = lane >> 4;
  const int l31 = lane & 31;
  const int rhalf = lane >> 5;
  const int wrow0 = blockIdx.x * 128 + wid * 32;

  const unsigned short* p0b[2]; const float* p0f[2];
  const unsigned short* p1b[2]; const float* p1f[2];
  const float* p2[2];
  #pragma unroll
  for (int mt = 0; mt < 2; ++mt) {
    int r = wrow0 + mt * 16 + l15;
    if (r >= M) r = M - 1;
    int r0 = i0 ? i0[r] : r;
    if constexpr (S0B) p0b[mt] = (const unsigned short*)s0v + (size_t)r0 * 128;
    else               p0f[mt] = (const float*)s0v + (size_t)r0 * 128;
    if constexpr (KDIM >= 256) {
      int r1 = i1 ? i1[r] : r;
      if constexpr (S1B) p1b[mt] = (const unsigned short*)s1v + (size_t)r1 * 128;
      else               p1f[mt] = (const float*)s1v + (size_t)r1 * 128;
    }
    if constexpr (KDIM >= 384) p2[mt] = s2 + (size_t)r * 128;
  }

  f32x4 acc[2][8] = {};
  constexpr int NSEG = KDIM / 128;

  #pragma unroll
  for (int seg = 0; seg < NSEG; ++seg) {
    // ---- prefetch ALL A fragments of this segment (8 x uint4) ----
    U16B a[2][4];
    #pragma unroll
    for (int mt = 0; mt < 2; ++mt) {
      #pragma unroll
      for (int k4 = 0; k4 < 4; ++k4) {
        const int kof = k4 * 32 + q * 8;  // element offset within segment
        if (seg == 0) {
          if constexpr (S0B) {
            a[mt][k4].u = *reinterpret_cast<const uint4*>(p0b[mt] + kof);
          } else {
            const float4* p = reinterpret_cast<const float4*>(p0f[mt] + kof);
            a[mt][k4].v = cvt8(p[0], p[1]);
          }
        } else if (seg == 1) {
          if constexpr (S1B) {
            a[mt][k4].u = *reinterpret_cast<const uint4*>(p1b[mt] + kof);
          } else {
            const float4* p = reinterpret_cast<const float4*>(p1f[mt] + kof);
            a[mt][k4].v = cvt8(p[0], p[1]);
          }
        } else {
          const float4* p = reinterpret_cast<const float4*>(p2[mt] + kof);
          a[mt][k4].v = cvt8(p[0], p[1]);
        }
      }
    }
    // ---- MFMA over the segment: 4 K-steps x 8 N-tiles x 2 M-tiles ----
    #pragma unroll
    for (int k4 = 0; k4 < 4; ++k4) {
      const int ksg = seg * 4 + k4;
      #pragma unroll
      for (int n = 0; n < 8; ++n) {
        U16B b;
        b.u = *reinterpret_cast<const uint4*>(Wb + (size_t)(n * 16 + l15) * KDIM + ksg * 32 + q * 8);
        acc[0][n] = __builtin_amdgcn_mfma_f32_16x16x32_bf16(a[0][k4].v, b.v, acc[0][n], 0, 0, 0);
        acc[1][n] = __builtin_amdgcn_mfma_f32_16x16x32_bf16(a[1][k4].v, b.v, acc[1][n], 0, 0, 0);
      }
    }
  }

  // ---- epilogue ----
  float bia[8], gam[8], bet[8];
  #pragma unroll
  for (int n = 0; n < 8; ++n) {
    int ch = n * 16 + l15;
    bia[n] = bias[ch]; gam[n] = gamma[ch]; bet[n] = beta[ch];
  }

  #pragma unroll
  for (int mt = 0; mt < 2; ++mt) {
    float vv[8][4];
    float sum[4] = {0.f, 0.f, 0.f, 0.f};
    float ssq[4] = {0.f, 0.f, 0.f, 0.f};
    #pragma unroll
    for (int n = 0; n < 8; ++n) {
      #pragma unroll
      for (int j = 0; j < 4; ++j) {
        float t = silu_f(silu_f(acc[mt][n][j] + bia[n]));
        vv[n][j] = t;
        sum[j] += t;
        ssq[j] += t * t;
      }
    }
    #pragma unroll
    for (int off = 1; off < 16; off <<= 1) {
      #pragma unroll
      for (int j = 0; j < 4; ++j) {
        sum[j] += __shfl_xor(sum[j], off);
        ssq[j] += __shfl_xor(ssq[j], off);
      }
    }
    float mu[4], rs[4];
    #pragma unroll
    for (int j = 0; j < 4; ++j) {
      mu[j] = sum[j] * (1.0f / 128.0f);
      float var = ssq[j] * (1.0f / 128.0f) - mu[j] * mu[j];
      rs[j] = rsqrtf(var + 1e-5f);
    }

    if (mt == 1) {
      asm volatile("s_waitcnt lgkmcnt(0)" ::: "memory");
    }
    #pragma unroll
    for (int n = 0; n < 8; ++n) {
      #pragma unroll
      for (int j = 0; j < 4; ++j) {
        float y = (vv[n][j] - mu[j]) * rs[j] * gam[n] + bet[n];
        BF1 c; c.h = (__bf16)y;
        yT[wid][q * 4 + j][n * 16 + l15] = c.s;
      }
    }
    asm volatile("s_waitcnt lgkmcnt(0)" ::: "memory");

    #pragma unroll
    for (int s = 0; s < 8; ++s) {
      int row16 = 2 * s + rhalf;
      int grow = wrow0 + mt * 16 + row16;
      uint2 w = *reinterpret_cast<const uint2*>(&yT[wid][row16][l31 * 4]);
      if (grow < M) {
        const f32x4 r4 = *reinterpret_cast<const f32x4*>(resid + (size_t)grow * 128 + l31 * 4);
        f32x4 o4;
        o4.x = r4.x + bfu2f(w.x & 0xffffu);
        o4.y = r4.y + bfu2f(w.x >> 16);
        o4.z = r4.z + bfu2f(w.y & 0xffffu);
        o4.w = r4.w + bfu2f(w.y >> 16);
        __builtin_nontemporal_store(o4, reinterpret_cast<f32x4*>(outp + (size_t)grow * 128 + l31 * 4));
        if constexpr (AGGR == 3) {
          int prow = prank[grow];
          *reinterpret_cast<uint2*>((unsigned short*)aggr + (size_t)prow * 128 + l31 * 4) = w;
        } else if constexpr (AGGR == 2) {
          int idx = aggr_idx[grow];
          unsigned short* ar = (unsigned short*)aggr + (size_t)idx * 128 + l31 * 4;
          asm volatile("global_atomic_pk_add_bf16 %0, %1, off" :: "v"(ar), "v"(w.x) : "memory");
          asm volatile("global_atomic_pk_add_bf16 %0, %1, off" :: "v"(ar + 2), "v"(w.y) : "memory");
        } else if constexpr (AGGR == 1) {
          int idx = aggr_idx[grow];
          float* ar = (float*)aggr + (size_t)idx * 128 + l31 * 4;
          atomicAdd(ar + 0, bfu2f(w.x & 0xffffu));
          atomicAdd(ar + 1, bfu2f(w.x >> 16));
          atomicAdd(ar + 2, bfu2f(w.y & 0xffffu));
          atomicAdd(ar + 3, bfu2f(w.y >> 16));
        }
      }
    }
  }
}

extern "C" void kernel_launch(void* const* d_in, const int* in_sizes, int n_in,
                              void* d_out, int out_size, void* d_ws, size_t ws_size,
                              hipStream_t stream) {
  const float* sender_x   = (const float*)d_in[0];
  const float* receiver_x = (const float*)d_in[1];
  const int*   edge_index = (const int*)d_in[2];
  const float* edge_attr  = (const float*)d_in[3];
  const float* We  = (const float*)d_in[4];
  const float* be  = (const float*)d_in[5];
  const float* ge  = (const float*)d_in[6];
  const float* bbe = (const float*)d_in[7];
  const float* Wn  = (const float*)d_in[8];
  const float* bn  = (const float*)d_in[9];
  const float* gn  = (const float*)d_in[10];
  const float* bbn = (const float*)d_in[11];
  const float* Ws  = (const float*)d_in[12];
  const float* bs  = (const float*)d_in[13];
  const float* gs  = (const float*)d_in[14];
  const float* bbs = (const float*)d_in[15];

  const int D  = 128;
  const int NS = in_sizes[0] / D;
  const int NR = in_sizes[1] / D;
  const int E  = in_sizes[2] / 2;

  const int* src = edge_index;
  const int* dst = edge_index + E;

  float* out          = (float*)d_out;
  float* sender_out   = out;
  float* receiver_out = out + (size_t)NS * D;
  float* edge_out     = out + (size_t)(NS + NR) * D;

  const size_t welems = 128 * 384 + 128 * 256 + 128 * 128;
  unsigned short* We_b = (unsigned short*)d_ws;
  unsigned short* Wn_b = We_b + 128 * 384;
  unsigned short* Ws_b = Wn_b + 128 * 256;
  unsigned short* sender_b   = We_b + welems;
  unsigned short* receiver_b = sender_b + (size_t)NS * D;
  unsigned short* aggr_b     = receiver_b + (size_t)NR * D;
  unsigned short* P_b        = aggr_b + (size_t)NR * D;
  int* counts    = (int*)(P_b + (size_t)E * D);
  int* pre       = counts + NR;
  int* offs      = pre + NR;
  int* cursor    = offs + NR;
  int* blockSums = cursor + NR;
  int* rank      = blockSums + 512;

  const int nScanBlocks = (NR + 1023) / 1024;
  const size_t needCSR = 2 * (welems + (size_t)(NS + 2 * NR) * D + (size_t)E * D)
                       + 4 * (4 * (size_t)NR + 512 + (size_t)E);
  const size_t needA = (welems + (size_t)(NS + 2 * NR) * D) * 2;
  const size_t needB = (welems + (size_t)NR * D) * 2;
  unsigned short* aggrB = We_b + welems;

  int tier;
  if (ws_size >= needCSR && nScanBlocks <= 512) tier = 0;
  else if (ws_size >= needA) tier = 1;
  else if (ws_size >= needB) tier = 2;
  else tier = 3;

  cvt_weights_kernel<<<(int)((welems + 255) / 256), 256, 0, stream>>>(We, Wn, Ws, We_b);

  const int gridE = (E + 127) / 128;
  const int gridR = (NR + 127) / 128;
  const int gridS = (NS + 127) / 128;
  const int n8s = NS * D / 8, n8r = NR * D / 8;

  if (tier == 0) {
    cvt_rows_kernel<<<(n8s + 255) / 256, 256, 0, stream>>>(sender_x, sender_b, n8s);
    cvt_rows_kernel<<<(n8r + 255) / 256, 256, 0, stream>>>(receiver_x, receiver_b, n8r);

    (void)hipMemsetAsync(counts, 0, (size_t)NR * 4, stream);
    hist_kernel<<<(E + 255) / 256, 256, 0, stream>>>(dst, counts, E);
    scan1_kernel<<<nScanBlocks, 256, 0, stream>>>(counts, pre, blockSums, NR);
    scan2_kernel<<<1, 512, 0, stream>>>(blockSums, nScanBlocks);
    scan3_kernel<<<(NR + 255) / 256, 256, 0, stream>>>(pre, blockSums, offs, cursor, NR);
    scatter_kernel<<<(E + 255) / 256, 256, 0, stream>>>(dst, cursor, rank, E);

    // 1) Edge MLP: writes edge_out + P rows at rank[e] (dst-sorted positions)
    mlp_rf3_kernel<384, 3, true, true><<<gridE, 256, 0, stream>>>(
        sender_b, src, receiver_b, dst, edge_attr,
        We_b, be, ge, bbe, edge_attr, edge_out, P_b, nullptr, rank, E);

    // 2) contiguous segment-sum
    agg_kernel<<<(NR + 7) / 8, 256, 0, stream>>>(P_b, offs, counts, aggr_b, NR);

    // 3) Node MLP
    mlp_rf3_kernel<256, 0, true, true><<<gridR, 256, 0, stream>>>(
        receiver_b, nullptr, aggr_b, nullptr, nullptr,
        Wn_b, bn, gn, bbn, receiver_x, receiver_out, nullptr, nullptr, nullptr, NR);

    // 4) Sender MLP
    mlp_rf3_kernel<128, 0, true, false><<<gridS, 256, 0, stream>>>(
        sender_b, nullptr, nullptr, nullptr, nullptr,
        Ws_b, bs, gs, bbs, sender_x, sender_out, nullptr, nullptr, nullptr, NS);
  } else if (tier == 1) {
    cvt_rows_kernel<<<(n8s + 255) / 256, 256, 0, stream>>>(sender_x, sender_b, n8s);
    cvt_rows_kernel<<<(n8r + 255) / 256, 256, 0, stream>>>(receiver_x, receiver_b, n8r);
    (void)hipMemsetAsync(aggr_b, 0, (size_t)NR * D * 2, stream);

    mlp_rf3_kernel<384, 2, true, true><<<gridE, 256, 0, stream>>>(
        sender_b, src, receiver_b, dst, edge_attr,
        We_b, be, ge, bbe, edge_attr, edge_out, aggr_b, dst, nullptr, E);

    mlp_rf3_kernel<256, 0, true, true><<<gridR, 256, 0, stream>>>(
        receiver_b, nullptr, aggr_b, nullptr, nullptr,
        Wn_b, bn, gn, bbn, receiver_x, receiver_out, nullptr, nullptr, nullptr, NR);

    mlp_rf3_kernel<128, 0, true, false><<<gridS, 256, 0, stream>>>(
        sender_b, nullptr, nullptr, nullptr, nullptr,
        Ws_b, bs, gs, bbs, sender_x, sender_out, nullptr, nullptr, nullptr, NS);
  } else if (tier == 2) {
    (void)hipMemsetAsync(aggrB, 0, (size_t)NR * D * 2, stream);

    mlp_rf3_kernel<384, 2, false, false><<<gridE, 256, 0, stream>>>(
        sender_x, src, receiver_x, dst, edge_attr,
        We_b, be, ge, bbe, edge_attr, edge_out, aggrB, dst, nullptr, E);

    mlp_rf3_kernel<256, 0, false, true><<<gridR, 256, 0, stream>>>(
        receiver_x, nullptr, aggrB, nullptr, nullptr,
        Wn_b, bn, gn, bbn, receiver_x, receiver_out, nullptr, nullptr, nullptr, NR);

    mlp_rf3_kernel<128, 0, false, false><<<gridS, 256, 0, stream>>>(
        sender_x, nullptr, nullptr, nullptr, nullptr,
        Ws_b, bs, gs, bbs, sender_x, sender_out, nullptr, nullptr, nullptr, NS);
  } else {
    (void)hipMemsetAsync(receiver_out, 0, (size_t)NR * D * sizeof(float), stream);

    mlp_rf3_kernel<384, 1, false, false><<<gridE, 256, 0, stream>>>(
        sender_x, src, receiver_x, dst, edge_attr,
        We_b, be, ge, bbe, edge_attr, edge_out, receiver_out, dst, nullptr, E);

    mlp_rf3_kernel<256, 0, false, false><<<gridR, 256, 0, stream>>>(
        receiver_x, nullptr, receiver_out, nullptr, nullptr,
        Wn_b, bn, gn, bbn, receiver_x, receiver_out, nullptr, nullptr, nullptr, NR);

    mlp_rf3_kernel<128, 0, false, false><<<gridS, 256, 0, stream>>>(
        sender_x, nullptr, nullptr, nullptr, nullptr,
        Ws_b, bs, gs, bbs, sender_x, sender_out, nullptr, nullptr, nullptr, NS);
  }
}

// Round 7
// 642.539 us; speedup vs baseline: 1.1588x; 1.0350x over previous
//
#include <hip/hip_runtime.h>
#include <stdint.h>

// ---------------------------------------------------------------------------
// GCastHeterocoder round 7: MFMA MLP with B staged in LDS per 128-col segment
// (zero vmem ops in the MFMA inner loop), A gathers prefetched one segment
// ahead in registers. CSR aggregation with rank-remapped sequential P.
// ---------------------------------------------------------------------------

typedef __bf16 bf16x8 __attribute__((ext_vector_type(8)));
typedef float  f32x4  __attribute__((ext_vector_type(4)));

union U16B { uint4 u; bf16x8 v; };
union BFPK { __bf16 h[2]; unsigned int u; };
union BF1  { __bf16 h; unsigned short s; };

__device__ __forceinline__ float silu_f(float x) {
  return x * __builtin_amdgcn_rcpf(1.0f + __expf(-x));
}
__device__ __forceinline__ float bfu2f(unsigned int lo16) {
  return __uint_as_float(lo16 << 16);
}
__device__ __forceinline__ bf16x8 cvt8(float4 a, float4 b) {
  bf16x8 r;
  r[0] = (__bf16)a.x; r[1] = (__bf16)a.y; r[2] = (__bf16)a.z; r[3] = (__bf16)a.w;
  r[4] = (__bf16)b.x; r[5] = (__bf16)b.y; r[6] = (__bf16)b.z; r[7] = (__bf16)b.w;
  return r;
}

// ---------------- weight / feature conversion ----------------
__global__ void cvt_weights_kernel(const float* __restrict__ We,
                                   const float* __restrict__ Wn,
                                   const float* __restrict__ Ws,
                                   unsigned short* __restrict__ out) {
  const int nWe = 128 * 384, nWn = 128 * 256, nWs = 128 * 128;
  int i = blockIdx.x * 256 + threadIdx.x;
  float f;
  if (i < nWe) f = We[i];
  else if (i < nWe + nWn) f = Wn[i - nWe];
  else if (i < nWe + nWn + nWs) f = Ws[i - nWe - nWn];
  else return;
  BF1 c; c.h = (__bf16)f;
  out[i] = c.s;
}

__global__ void cvt_rows_kernel(const float* __restrict__ in,
                                unsigned short* __restrict__ out, int n8) {
  int i = blockIdx.x * 256 + threadIdx.x;
  if (i >= n8) return;
  float4 a = reinterpret_cast<const float4*>(in)[2 * i];
  float4 b = reinterpret_cast<const float4*>(in)[2 * i + 1];
  U16B r; r.v = cvt8(a, b);
  reinterpret_cast<uint4*>(out)[i] = r.u;
}

// ---------------- CSR build ----------------
__global__ void hist_kernel(const int* __restrict__ dst, int* __restrict__ counts, int E) {
  int i = blockIdx.x * 256 + threadIdx.x;
  if (i < E) atomicAdd(&counts[dst[i]], 1);
}

__global__ void scan1_kernel(const int* __restrict__ counts, int* __restrict__ pre,
                             int* __restrict__ blockSums, int n) {
  __shared__ int sh[256];
  const int t = threadIdx.x;
  const int base = blockIdx.x * 1024 + t * 4;
  int c0 = (base + 0 < n) ? counts[base + 0] : 0;
  int c1 = (base + 1 < n) ? counts[base + 1] : 0;
  int c2 = (base + 2 < n) ? counts[base + 2] : 0;
  int c3 = (base + 3 < n) ? counts[base + 3] : 0;
  int tot = c0 + c1 + c2 + c3;
  sh[t] = tot;
  __syncthreads();
  #pragma unroll
  for (int off = 1; off < 256; off <<= 1) {
    int v = (t >= off) ? sh[t - off] : 0;
    __syncthreads();
    sh[t] += v;
    __syncthreads();
  }
  int excl = sh[t] - tot;
  if (base + 0 < n) pre[base + 0] = excl;
  if (base + 1 < n) pre[base + 1] = excl + c0;
  if (base + 2 < n) pre[base + 2] = excl + c0 + c1;
  if (base + 3 < n) pre[base + 3] = excl + c0 + c1 + c2;
  if (t == 255) blockSums[blockIdx.x] = sh[255];
}

__global__ void scan2_kernel(int* __restrict__ blockSums, int nb) {
  __shared__ int sh[512];
  const int t = threadIdx.x;
  int v = (t < nb) ? blockSums[t] : 0;
  sh[t] = v;
  __syncthreads();
  #pragma unroll
  for (int off = 1; off < 512; off <<= 1) {
    int u = (t >= off) ? sh[t - off] : 0;
    __syncthreads();
    sh[t] += u;
    __syncthreads();
  }
  if (t < nb) blockSums[t] = sh[t] - v;
}

__global__ void scan3_kernel(const int* __restrict__ pre, const int* __restrict__ blockSums,
                             int* __restrict__ offs, int* __restrict__ cursor, int n) {
  int i = blockIdx.x * 256 + threadIdx.x;
  if (i >= n) return;
  int o = pre[i] + blockSums[i >> 10];
  offs[i] = o;
  cursor[i] = o;
}

__global__ void scatter_kernel(const int* __restrict__ dst, int* __restrict__ cursor,
                               int* __restrict__ rank, int E) {
  int i = blockIdx.x * 256 + threadIdx.x;
  if (i < E) {
    int p = atomicAdd(&cursor[dst[i]], 1);
    rank[i] = p;
  }
}

// segment sum over CONTIGUOUS P rows [offs[r], offs[r]+counts[r])
__global__ __launch_bounds__(256) void agg_kernel(
    const unsigned short* __restrict__ P,
    const int* __restrict__ offs, const int* __restrict__ counts,
    unsigned short* __restrict__ aggr, int NR) {
  const int l = threadIdx.x & 31;
  const int g0 = (blockIdx.x * 256 + threadIdx.x) >> 5;
  if (g0 >= NR) return;
  int beg = offs[g0];
  int cnt = counts[g0];
  float s0 = 0.f, s1 = 0.f, s2 = 0.f, s3 = 0.f;
  const unsigned short* p = P + (size_t)beg * 128 + l * 4;
  for (int k = 0; k < cnt; ++k) {
    uint2 w = *reinterpret_cast<const uint2*>(p);
    p += 128;
    s0 += bfu2f(w.x & 0xffffu);
    s1 += bfu2f(w.x >> 16);
    s2 += bfu2f(w.y & 0xffffu);
    s3 += bfu2f(w.y >> 16);
  }
  BFPK a, b;
  a.h[0] = (__bf16)s0; a.h[1] = (__bf16)s1;
  b.h[0] = (__bf16)s2; b.h[1] = (__bf16)s3;
  uint2 o; o.x = a.u; o.y = b.u;
  *reinterpret_cast<uint2*>(aggr + (size_t)g0 * 128 + l * 4) = o;
}

// ---------------------------------------------------------------------------
// Fused GCastMLP, B in LDS. AGGR: 0=none, 1=fp32 atomicAdd, 2=pk bf16 atomics,
// 3=write P row (bf16) at prank[grow]. S0B/S1B: segment dtype bf16.
// 256 thr / 4 waves, 128 rows/block. B staged per 128-col segment into LDS
// (padded rows, zero vmem in MFMA loop); A prefetched one segment ahead.
// ---------------------------------------------------------------------------
template <int KDIM, int AGGR, bool S0B, bool S1B>
__global__ __launch_bounds__(256, 2) void mlp_lds_kernel(
    const void* __restrict__ s0v, const int* __restrict__ i0,
    const void* __restrict__ s1v, const int* __restrict__ i1,
    const float* __restrict__ s2,
    const unsigned short* __restrict__ Wb,
    const float* __restrict__ bias, const float* __restrict__ gamma,
    const float* __restrict__ beta,
    const float* __restrict__ resid,
    float* __restrict__ outp,
    void* aggr, const int* __restrict__ aggr_idx,
    const int* __restrict__ prank,
    int M) {
  constexpr int LDP = 136;  // 272 B row stride: 16B-aligned, bank-rotating
  __shared__ __align__(16) unsigned short smem[128 * LDP];  // 34.8 KB; yT overlay in epilogue

  const int tid = threadIdx.x;
  const int wid = tid >> 6;
  const int lane = tid & 63;
  const int l15 = lane & 15;
  const int q = lane >> 4;
  const int l31 = lane & 31;
  const int rhalf = lane >> 5;
  const int wrow0 = blockIdx.x * 128 + wid * 32;
  const int srow = tid >> 1;   // B-stage: 2 threads per weight row
  const int shalf = tid & 1;

  const unsigned short* p0b[2]; const float* p0f[2];
  const unsigned short* p1b[2]; const float* p1f[2];
  const float* p2[2];
  #pragma unroll
  for (int mt = 0; mt < 2; ++mt) {
    int r = wrow0 + mt * 16 + l15;
    if (r >= M) r = M - 1;  // clamp tail; stores masked later
    int r0 = i0 ? i0[r] : r;
    if constexpr (S0B) p0b[mt] = (const unsigned short*)s0v + (size_t)r0 * 128;
    else               p0f[mt] = (const float*)s0v + (size_t)r0 * 128;
    if constexpr (KDIM >= 256) {
      int r1 = i1 ? i1[r] : r;
      if constexpr (S1B) p1b[mt] = (const unsigned short*)s1v + (size_t)r1 * 128;
      else               p1f[mt] = (const float*)s1v + (size_t)r1 * 128;
    }
    if constexpr (KDIM >= 384) p2[mt] = s2 + (size_t)r * 128;
  }

  f32x4 acc[2][8] = {};
  constexpr int NSEG = KDIM / 128;

  uint4 bst[8];
  auto loadB = [&](int seg) {
    #pragma unroll
    for (int u = 0; u < 8; ++u)
      bst[u] = *reinterpret_cast<const uint4*>(Wb + (size_t)srow * KDIM + seg * 128 + shalf * 64 + u * 8);
  };
  auto writeB = [&]() {
    #pragma unroll
    for (int u = 0; u < 8; ++u)
      *reinterpret_cast<uint4*>(&smem[srow * LDP + shalf * 64 + u * 8]) = bst[u];
  };
  U16B Acur[2][4], Anxt[2][4];
  auto loadSeg = [&](int seg, U16B (&out)[2][4]) {
    #pragma unroll
    for (int mt = 0; mt < 2; ++mt) {
      #pragma unroll
      for (int k4 = 0; k4 < 4; ++k4) {
        const int kof = k4 * 32 + q * 8;
        if (seg == 0) {
          if constexpr (S0B) {
            out[mt][k4].u = *reinterpret_cast<const uint4*>(p0b[mt] + kof);
          } else {
            const float4* p = reinterpret_cast<const float4*>(p0f[mt] + kof);
            out[mt][k4].v = cvt8(p[0], p[1]);
          }
        } else if (seg == 1) {
          if constexpr (S1B) {
            out[mt][k4].u = *reinterpret_cast<const uint4*>(p1b[mt] + kof);
          } else {
            const float4* p = reinterpret_cast<const float4*>(p1f[mt] + kof);
            out[mt][k4].v = cvt8(p[0], p[1]);
          }
        } else {
          const float4* p = reinterpret_cast<const float4*>(p2[mt] + kof);
          out[mt][k4].v = cvt8(p[0], p[1]);
        }
      }
    }
  };

  loadB(0);
  loadSeg(0, Acur);
  writeB();
  __syncthreads();

  #pragma unroll
  for (int seg = 0; seg < NSEG; ++seg) {
    if (seg + 1 < NSEG) {
      loadB(seg + 1);       // in flight across this segment's MFMA
      loadSeg(seg + 1, Anxt);
    }
    #pragma unroll
    for (int k4 = 0; k4 < 4; ++k4) {
      #pragma unroll
      for (int n = 0; n < 8; ++n) {
        U16B b;
        b.u = *reinterpret_cast<const uint4*>(&smem[(n * 16 + l15) * LDP + k4 * 32 + q * 8]);
        acc[0][n] = __builtin_amdgcn_mfma_f32_16x16x32_bf16(Acur[0][k4].v, b.v, acc[0][n], 0, 0, 0);
        acc[1][n] = __builtin_amdgcn_mfma_f32_16x16x32_bf16(Acur[1][k4].v, b.v, acc[1][n], 0, 0, 0);
      }
    }
    __syncthreads();        // all waves done reading this B segment
    if (seg + 1 < NSEG) {
      writeB();
      __syncthreads();      // B segment staged for everyone
      #pragma unroll
      for (int mt = 0; mt < 2; ++mt)
        #pragma unroll
        for (int k4 = 0; k4 < 4; ++k4)
          Acur[mt][k4] = Anxt[mt][k4];
    }
  }

  // ---- epilogue (yT overlays smem; final barrier above protects B) ----
  using YT = unsigned short (*)[16][132];
  YT yT = reinterpret_cast<YT>(smem);

  float bia[8], gam[8], bet[8];
  #pragma unroll
  for (int n = 0; n < 8; ++n) {
    int ch = n * 16 + l15;
    bia[n] = bias[ch]; gam[n] = gamma[ch]; bet[n] = beta[ch];
  }

  #pragma unroll
  for (int mt = 0; mt < 2; ++mt) {
    float vv[8][4];
    float sum[4] = {0.f, 0.f, 0.f, 0.f};
    float ssq[4] = {0.f, 0.f, 0.f, 0.f};
    #pragma unroll
    for (int n = 0; n < 8; ++n) {
      #pragma unroll
      for (int j = 0; j < 4; ++j) {
        float t = silu_f(silu_f(acc[mt][n][j] + bia[n]));
        vv[n][j] = t;
        sum[j] += t;
        ssq[j] += t * t;
      }
    }
    #pragma unroll
    for (int off = 1; off < 16; off <<= 1) {
      #pragma unroll
      for (int j = 0; j < 4; ++j) {
        sum[j] += __shfl_xor(sum[j], off);
        ssq[j] += __shfl_xor(ssq[j], off);
      }
    }
    float mu[4], rs[4];
    #pragma unroll
    for (int j = 0; j < 4; ++j) {
      mu[j] = sum[j] * (1.0f / 128.0f);
      float var = ssq[j] * (1.0f / 128.0f) - mu[j] * mu[j];
      rs[j] = rsqrtf(var + 1e-5f);
    }

    if (mt == 1) {  // WAR guard: mt0 LDS reads must complete before overwrite
      asm volatile("s_waitcnt lgkmcnt(0)" ::: "memory");
    }
    #pragma unroll
    for (int n = 0; n < 8; ++n) {
      #pragma unroll
      for (int j = 0; j < 4; ++j) {
        float y = (vv[n][j] - mu[j]) * rs[j] * gam[n] + bet[n];
        BF1 c; c.h = (__bf16)y;
        yT[wid][q * 4 + j][n * 16 + l15] = c.s;
      }
    }
    asm volatile("s_waitcnt lgkmcnt(0)" ::: "memory");

    #pragma unroll
    for (int s = 0; s < 8; ++s) {
      int row16 = 2 * s + rhalf;
      int grow = wrow0 + mt * 16 + row16;
      uint2 w = *reinterpret_cast<const uint2*>(&yT[wid][row16][l31 * 4]);
      if (grow < M) {
        const f32x4 r4 = *reinterpret_cast<const f32x4*>(resid + (size_t)grow * 128 + l31 * 4);
        f32x4 o4;
        o4.x = r4.x + bfu2f(w.x & 0xffffu);
        o4.y = r4.y + bfu2f(w.x >> 16);
        o4.z = r4.z + bfu2f(w.y & 0xffffu);
        o4.w = r4.w + bfu2f(w.y >> 16);
        __builtin_nontemporal_store(o4, reinterpret_cast<f32x4*>(outp + (size_t)grow * 128 + l31 * 4));
        if constexpr (AGGR == 3) {
          int prow = prank[grow];
          *reinterpret_cast<uint2*>((unsigned short*)aggr + (size_t)prow * 128 + l31 * 4) = w;
        } else if constexpr (AGGR == 2) {
          int idx = aggr_idx[grow];
          unsigned short* ar = (unsigned short*)aggr + (size_t)idx * 128 + l31 * 4;
          asm volatile("global_atomic_pk_add_bf16 %0, %1, off" :: "v"(ar), "v"(w.x) : "memory");
          asm volatile("global_atomic_pk_add_bf16 %0, %1, off" :: "v"(ar + 2), "v"(w.y) : "memory");
        } else if constexpr (AGGR == 1) {
          int idx = aggr_idx[grow];
          float* ar = (float*)aggr + (size_t)idx * 128 + l31 * 4;
          atomicAdd(ar + 0, bfu2f(w.x & 0xffffu));
          atomicAdd(ar + 1, bfu2f(w.x >> 16));
          atomicAdd(ar + 2, bfu2f(w.y & 0xffffu));
          atomicAdd(ar + 3, bfu2f(w.y >> 16));
        }
      }
    }
  }
}

extern "C" void kernel_launch(void* const* d_in, const int* in_sizes, int n_in,
                              void* d_out, int out_size, void* d_ws, size_t ws_size,
                              hipStream_t stream) {
  const float* sender_x   = (const float*)d_in[0];
  const float* receiver_x = (const float*)d_in[1];
  const int*   edge_index = (const int*)d_in[2];
  const float* edge_attr  = (const float*)d_in[3];
  const float* We  = (const float*)d_in[4];
  const float* be  = (const float*)d_in[5];
  const float* ge  = (const float*)d_in[6];
  const float* bbe = (const float*)d_in[7];
  const float* Wn  = (const float*)d_in[8];
  const float* bn  = (const float*)d_in[9];
  const float* gn  = (const float*)d_in[10];
  const float* bbn = (const float*)d_in[11];
  const float* Ws  = (const float*)d_in[12];
  const float* bs  = (const float*)d_in[13];
  const float* gs  = (const float*)d_in[14];
  const float* bbs = (const float*)d_in[15];

  const int D  = 128;
  const int NS = in_sizes[0] / D;
  const int NR = in_sizes[1] / D;
  const int E  = in_sizes[2] / 2;

  const int* src = edge_index;
  const int* dst = edge_index + E;

  float* out          = (float*)d_out;
  float* sender_out   = out;
  float* receiver_out = out + (size_t)NS * D;
  float* edge_out     = out + (size_t)(NS + NR) * D;

  const size_t welems = 128 * 384 + 128 * 256 + 128 * 128;
  unsigned short* We_b = (unsigned short*)d_ws;
  unsigned short* Wn_b = We_b + 128 * 384;
  unsigned short* Ws_b = Wn_b + 128 * 256;
  unsigned short* sender_b   = We_b + welems;
  unsigned short* receiver_b = sender_b + (size_t)NS * D;
  unsigned short* aggr_b     = receiver_b + (size_t)NR * D;
  unsigned short* P_b        = aggr_b + (size_t)NR * D;
  int* counts    = (int*)(P_b + (size_t)E * D);
  int* pre       = counts + NR;
  int* offs      = pre + NR;
  int* cursor    = offs + NR;
  int* blockSums = cursor + NR;
  int* rank      = blockSums + 512;

  const int nScanBlocks = (NR + 1023) / 1024;
  const size_t needCSR = 2 * (welems + (size_t)(NS + 2 * NR) * D + (size_t)E * D)
                       + 4 * (4 * (size_t)NR + 512 + (size_t)E);
  const size_t needA = (welems + (size_t)(NS + 2 * NR) * D) * 2;
  const size_t needB = (welems + (size_t)NR * D) * 2;
  unsigned short* aggrB = We_b + welems;

  int tier;
  if (ws_size >= needCSR && nScanBlocks <= 512) tier = 0;
  else if (ws_size >= needA) tier = 1;
  else if (ws_size >= needB) tier = 2;
  else tier = 3;

  cvt_weights_kernel<<<(int)((welems + 255) / 256), 256, 0, stream>>>(We, Wn, Ws, We_b);

  const int gridE = (E + 127) / 128;
  const int gridR = (NR + 127) / 128;
  const int gridS = (NS + 127) / 128;
  const int n8s = NS * D / 8, n8r = NR * D / 8;

  if (tier == 0) {
    cvt_rows_kernel<<<(n8s + 255) / 256, 256, 0, stream>>>(sender_x, sender_b, n8s);
    cvt_rows_kernel<<<(n8r + 255) / 256, 256, 0, stream>>>(receiver_x, receiver_b, n8r);

    (void)hipMemsetAsync(counts, 0, (size_t)NR * 4, stream);
    hist_kernel<<<(E + 255) / 256, 256, 0, stream>>>(dst, counts, E);
    scan1_kernel<<<nScanBlocks, 256, 0, stream>>>(counts, pre, blockSums, NR);
    scan2_kernel<<<1, 512, 0, stream>>>(blockSums, nScanBlocks);
    scan3_kernel<<<(NR + 255) / 256, 256, 0, stream>>>(pre, blockSums, offs, cursor, NR);
    scatter_kernel<<<(E + 255) / 256, 256, 0, stream>>>(dst, cursor, rank, E);

    mlp_lds_kernel<384, 3, true, true><<<gridE, 256, 0, stream>>>(
        sender_b, src, receiver_b, dst, edge_attr,
        We_b, be, ge, bbe, edge_attr, edge_out, P_b, nullptr, rank, E);

    agg_kernel<<<(NR + 7) / 8, 256, 0, stream>>>(P_b, offs, counts, aggr_b, NR);

    mlp_lds_kernel<256, 0, true, true><<<gridR, 256, 0, stream>>>(
        receiver_b, nullptr, aggr_b, nullptr, nullptr,
        Wn_b, bn, gn, bbn, receiver_x, receiver_out, nullptr, nullptr, nullptr, NR);

    mlp_lds_kernel<128, 0, true, false><<<gridS, 256, 0, stream>>>(
        sender_b, nullptr, nullptr, nullptr, nullptr,
        Ws_b, bs, gs, bbs, sender_x, sender_out, nullptr, nullptr, nullptr, NS);
  } else if (tier == 1) {
    cvt_rows_kernel<<<(n8s + 255) / 256, 256, 0, stream>>>(sender_x, sender_b, n8s);
    cvt_rows_kernel<<<(n8r + 255) / 256, 256, 0, stream>>>(receiver_x, receiver_b, n8r);
    (void)hipMemsetAsync(aggr_b, 0, (size_t)NR * D * 2, stream);

    mlp_lds_kernel<384, 2, true, true><<<gridE, 256, 0, stream>>>(
        sender_b, src, receiver_b, dst, edge_attr,
        We_b, be, ge, bbe, edge_attr, edge_out, aggr_b, dst, nullptr, E);

    mlp_lds_kernel<256, 0, true, true><<<gridR, 256, 0, stream>>>(
        receiver_b, nullptr, aggr_b, nullptr, nullptr,
        Wn_b, bn, gn, bbn, receiver_x, receiver_out, nullptr, nullptr, nullptr, NR);

    mlp_lds_kernel<128, 0, true, false><<<gridS, 256, 0, stream>>>(
        sender_b, nullptr, nullptr, nullptr, nullptr,
        Ws_b, bs, gs, bbs, sender_x, sender_out, nullptr, nullptr, nullptr, NS);
  } else if (tier == 2) {
    (void)hipMemsetAsync(aggrB, 0, (size_t)NR * D * 2, stream);

    mlp_lds_kernel<384, 2, false, false><<<gridE, 256, 0, stream>>>(
        sender_x, src, receiver_x, dst, edge_attr,
        We_b, be, ge, bbe, edge_attr, edge_out, aggrB, dst, nullptr, E);

    mlp_lds_kernel<256, 0, false, true><<<gridR, 256, 0, stream>>>(
        receiver_x, nullptr, aggrB, nullptr, nullptr,
        Wn_b, bn, gn, bbn, receiver_x, receiver_out, nullptr, nullptr, nullptr, NR);

    mlp_lds_kernel<128, 0, false, false><<<gridS, 256, 0, stream>>>(
        sender_x, nullptr, nullptr, nullptr, nullptr,
        Ws_b, bs, gs, bbs, sender_x, sender_out, nullptr, nullptr, nullptr, NS);
  } else {
    (void)hipMemsetAsync(receiver_out, 0, (size_t)NR * D * sizeof(float), stream);

    mlp_lds_kernel<384, 1, false, false><<<gridE, 256, 0, stream>>>(
        sender_x, src, receiver_x, dst, edge_attr,
        We_b, be, ge, bbe, edge_attr, edge_out, receiver_out, dst, nullptr, E);

    mlp_lds_kernel<256, 0, false, false><<<gridR, 256, 0, stream>>>(
        receiver_x, nullptr, receiver_out, nullptr, nullptr,
        Wn_b, bn, gn, bbn, receiver_x, receiver_out, nullptr, nullptr, nullptr, NR);

    mlp_lds_kernel<128, 0, false, false><<<gridS, 256, 0, stream>>>(
        sender_x, nullptr, nullptr, nullptr, nullptr,
        Ws_b, bs, gs, bbs, sender_x, sender_out, nullptr, nullptr, nullptr, NS);
  }
}

// Round 8
// 461.561 us; speedup vs baseline: 1.6131x; 1.3921x over previous
//
#include <hip/hip_runtime.h>
#include <stdint.h>

// ---------------------------------------------------------------------------
// GCastHeterocoder round 8: MFMA MLP, B via global_load_lds into double-
// buffered LDS (pre-swizzled weight image in ws -> conflict-minimal ds_read),
// 8 waves x 1 m-tile (16 rows) per 512-thr block, launch_bounds(512,4) for
// 16 waves/CU. CSR aggregation with rank-remapped sequential P.
// ---------------------------------------------------------------------------

typedef __bf16 bf16x8 __attribute__((ext_vector_type(8)));
typedef float  f32x4  __attribute__((ext_vector_type(4)));

union U16B { uint4 u; bf16x8 v; };
union BFPK { __bf16 h[2]; unsigned int u; };
union BF1  { __bf16 h; unsigned short s; };

__device__ __forceinline__ float silu_f(float x) {
  return x * __builtin_amdgcn_rcpf(1.0f + __expf(-x));
}
__device__ __forceinline__ float bfu2f(unsigned int lo16) {
  return __uint_as_float(lo16 << 16);
}
__device__ __forceinline__ bf16x8 cvt8(float4 a, float4 b) {
  bf16x8 r;
  r[0] = (__bf16)a.x; r[1] = (__bf16)a.y; r[2] = (__bf16)a.z; r[3] = (__bf16)a.w;
  r[4] = (__bf16)b.x; r[5] = (__bf16)b.y; r[6] = (__bf16)b.z; r[7] = (__bf16)b.w;
  return r;
}

// ---------------- weight conversion: fp32 -> SWIZZLED bf16 image ----------
// Image: 6 panels of [128 rows][128 cols], panel p stores (We seg0..2,
// Wn seg0..1, Ws). Within a row, byte offset b holds W[row][ (b^((row&7)<<4))/2 ].
__global__ void cvt_weights_kernel(const float* __restrict__ We,
                                   const float* __restrict__ Wn,
                                   const float* __restrict__ Ws,
                                   unsigned short* __restrict__ out) {
  int i = blockIdx.x * 256 + threadIdx.x;  // ushort index over 6*16384
  if (i >= 6 * 16384) return;
  int panel = i >> 14;
  int r = (i >> 7) & 127;
  int csw = i & 127;
  int c_or = ((csw * 2) ^ ((r & 7) << 4)) >> 1;
  float f;
  if (panel < 3)      f = We[r * 384 + panel * 128 + c_or];
  else if (panel < 5) f = Wn[r * 256 + (panel - 3) * 128 + c_or];
  else                f = Ws[r * 128 + c_or];
  BF1 c; c.h = (__bf16)f;
  out[i] = c.s;
}

__global__ void cvt_rows_kernel(const float* __restrict__ in,
                                unsigned short* __restrict__ out, int n8) {
  int i = blockIdx.x * 256 + threadIdx.x;
  if (i >= n8) return;
  float4 a = reinterpret_cast<const float4*>(in)[2 * i];
  float4 b = reinterpret_cast<const float4*>(in)[2 * i + 1];
  U16B r; r.v = cvt8(a, b);
  reinterpret_cast<uint4*>(out)[i] = r.u;
}

// ---------------- CSR build ----------------
__global__ void hist_kernel(const int* __restrict__ dst, int* __restrict__ counts, int E) {
  int i = blockIdx.x * 256 + threadIdx.x;
  if (i < E) atomicAdd(&counts[dst[i]], 1);
}

__global__ void scan1_kernel(const int* __restrict__ counts, int* __restrict__ pre,
                             int* __restrict__ blockSums, int n) {
  __shared__ int sh[256];
  const int t = threadIdx.x;
  const int base = blockIdx.x * 1024 + t * 4;
  int c0 = (base + 0 < n) ? counts[base + 0] : 0;
  int c1 = (base + 1 < n) ? counts[base + 1] : 0;
  int c2 = (base + 2 < n) ? counts[base + 2] : 0;
  int c3 = (base + 3 < n) ? counts[base + 3] : 0;
  int tot = c0 + c1 + c2 + c3;
  sh[t] = tot;
  __syncthreads();
  #pragma unroll
  for (int off = 1; off < 256; off <<= 1) {
    int v = (t >= off) ? sh[t - off] : 0;
    __syncthreads();
    sh[t] += v;
    __syncthreads();
  }
  int excl = sh[t] - tot;
  if (base + 0 < n) pre[base + 0] = excl;
  if (base + 1 < n) pre[base + 1] = excl + c0;
  if (base + 2 < n) pre[base + 2] = excl + c0 + c1;
  if (base + 3 < n) pre[base + 3] = excl + c0 + c1 + c2;
  if (t == 255) blockSums[blockIdx.x] = sh[255];
}

__global__ void scan2_kernel(int* __restrict__ blockSums, int nb) {
  __shared__ int sh[512];
  const int t = threadIdx.x;
  int v = (t < nb) ? blockSums[t] : 0;
  sh[t] = v;
  __syncthreads();
  #pragma unroll
  for (int off = 1; off < 512; off <<= 1) {
    int u = (t >= off) ? sh[t - off] : 0;
    __syncthreads();
    sh[t] += u;
    __syncthreads();
  }
  if (t < nb) blockSums[t] = sh[t] - v;
}

__global__ void scan3_kernel(const int* __restrict__ pre, const int* __restrict__ blockSums,
                             int* __restrict__ offs, int* __restrict__ cursor, int n) {
  int i = blockIdx.x * 256 + threadIdx.x;
  if (i >= n) return;
  int o = pre[i] + blockSums[i >> 10];
  offs[i] = o;
  cursor[i] = o;
}

__global__ void scatter_kernel(const int* __restrict__ dst, int* __restrict__ cursor,
                               int* __restrict__ rank, int E) {
  int i = blockIdx.x * 256 + threadIdx.x;
  if (i < E) {
    int p = atomicAdd(&cursor[dst[i]], 1);
    rank[i] = p;
  }
}

// segment sum over CONTIGUOUS P rows [offs[r], offs[r]+counts[r])
__global__ __launch_bounds__(256) void agg_kernel(
    const unsigned short* __restrict__ P,
    const int* __restrict__ offs, const int* __restrict__ counts,
    unsigned short* __restrict__ aggr, int NR) {
  const int l = threadIdx.x & 31;
  const int g0 = (blockIdx.x * 256 + threadIdx.x) >> 5;
  if (g0 >= NR) return;
  int beg = offs[g0];
  int cnt = counts[g0];
  float s0 = 0.f, s1 = 0.f, s2 = 0.f, s3 = 0.f;
  const unsigned short* p = P + (size_t)beg * 128 + l * 4;
  for (int k = 0; k < cnt; ++k) {
    uint2 w = *reinterpret_cast<const uint2*>(p);
    p += 128;
    s0 += bfu2f(w.x & 0xffffu);
    s1 += bfu2f(w.x >> 16);
    s2 += bfu2f(w.y & 0xffffu);
    s3 += bfu2f(w.y >> 16);
  }
  BFPK a, b;
  a.h[0] = (__bf16)s0; a.h[1] = (__bf16)s1;
  b.h[0] = (__bf16)s2; b.h[1] = (__bf16)s3;
  uint2 o; o.x = a.u; o.y = b.u;
  *reinterpret_cast<uint2*>(aggr + (size_t)g0 * 128 + l * 4) = o;
}

// ---------------------------------------------------------------------------
// Fused GCastMLP v8. 512 thr / 8 waves, 128 rows/block (wave owns 16 rows).
// B: global_load_lds into double-buffered LDS (swizzled image). A: register
// prefetch one segment ahead. AGGR: 0=none, 1=fp32 atomics, 2=pk bf16
// atomics, 3=P row at prank[grow]. S0B/S1B: segment dtype bf16.
// ---------------------------------------------------------------------------
template <int KDIM, int AGGR, bool S0B, bool S1B>
__global__ __launch_bounds__(512, 4) void mlp_v8_kernel(
    const void* __restrict__ s0v, const int* __restrict__ i0,
    const void* __restrict__ s1v, const int* __restrict__ i1,
    const float* __restrict__ s2,
    const unsigned short* __restrict__ Wb,   // swizzled image, NSEG panels
    const float* __restrict__ bias, const float* __restrict__ gamma,
    const float* __restrict__ beta,
    const float* __restrict__ resid,
    float* __restrict__ outp,
    void* aggr, const int* __restrict__ aggr_idx,
    const int* __restrict__ prank,
    int M) {
  constexpr int NSEG = KDIM / 128;
  __shared__ __align__(16) unsigned short smem[2][16384];  // 64 KB dbuf

  const int tid = threadIdx.x;
  const int wid = tid >> 6;        // 0..7
  const int lane = tid & 63;
  const int l15 = lane & 15;
  const int q = lane >> 4;
  const int l31 = lane & 31;
  const int rhalf = lane >> 5;
  const int wrow = blockIdx.x * 128 + wid * 16;
  const int xm = (l15 & 7) << 3;   // ushort-unit XOR mask for swizzled read

  // A row pointers (single m-tile: row = wrow + l15)
  int rr = wrow + l15;
  if (rr >= M) rr = M - 1;  // clamp tail; stores masked later
  const unsigned short* p0b; const float* p0f;
  const unsigned short* p1b = nullptr; const float* p1f = nullptr;
  const float* p2 = nullptr;
  {
    int r0 = i0 ? i0[rr] : rr;
    if constexpr (S0B) p0b = (const unsigned short*)s0v + (size_t)r0 * 128;
    else               p0f = (const float*)s0v + (size_t)r0 * 128;
    if constexpr (KDIM >= 256) {
      int r1 = i1 ? i1[rr] : rr;
      if constexpr (S1B) p1b = (const unsigned short*)s1v + (size_t)r1 * 128;
      else               p1f = (const float*)s1v + (size_t)r1 * 128;
    }
    if constexpr (KDIM >= 384) p2 = s2 + (size_t)rr * 128;
  }

  f32x4 acc[8] = {};

  // stage one 32 KB B panel via global_load_lds (4 instrs/wave, 1 KB each)
  auto stageB = [&](int seg, int buf) {
    const unsigned short* g = Wb + seg * 16384 + wid * 2048 + lane * 8;
    unsigned short* l = &smem[buf][wid * 2048];
    #pragma unroll
    for (int u = 0; u < 4; ++u) {
      __builtin_amdgcn_global_load_lds(
          (const __attribute__((address_space(1))) unsigned int*)(g + u * 512),
          (__attribute__((address_space(3))) unsigned int*)(l + u * 512),
          16, 0, 0);
    }
  };

  U16B Ac[4], An[4];
  auto loadA = [&](int seg, U16B (&dst)[4]) {
    #pragma unroll
    for (int k4 = 0; k4 < 4; ++k4) {
      const int kof = k4 * 32 + q * 8;
      if (seg == 0) {
        if constexpr (S0B) {
          dst[k4].u = *reinterpret_cast<const uint4*>(p0b + kof);
        } else {
          const float4* p = reinterpret_cast<const float4*>(p0f + kof);
          dst[k4].v = cvt8(p[0], p[1]);
        }
      } else if (seg == 1) {
        if constexpr (S1B) {
          dst[k4].u = *reinterpret_cast<const uint4*>(p1b + kof);
        } else {
          const float4* p = reinterpret_cast<const float4*>(p1f + kof);
          dst[k4].v = cvt8(p[0], p[1]);
        }
      } else {
        const float4* p = reinterpret_cast<const float4*>(p2 + kof);
        dst[k4].v = cvt8(p[0], p[1]);
      }
    }
  };

  stageB(0, 0);
  loadA(0, Ac);
  __syncthreads();  // compiler drains vmcnt(0): B0 in LDS

  int cur = 0;
  #pragma unroll
  for (int seg = 0; seg < NSEG; ++seg) {
    if (seg + 1 < NSEG) {
      stageB(seg + 1, cur ^ 1);   // in flight over this segment's MFMA
      loadA(seg + 1, An);
    }
    #pragma unroll
    for (int k4 = 0; k4 < 4; ++k4) {
      #pragma unroll
      for (int n = 0; n < 8; ++n) {
        U16B b;
        b.u = *reinterpret_cast<const uint4*>(
            &smem[cur][(n * 16 + l15) * 128 + ((k4 * 32 + q * 8) ^ xm)]);
        acc[n] = __builtin_amdgcn_mfma_f32_16x16x32_bf16(Ac[k4].v, b.v, acc[n], 0, 0, 0);
      }
    }
    __syncthreads();              // all reads of buf done; next B/A landed
    if (seg + 1 < NSEG) {
      #pragma unroll
      for (int k4 = 0; k4 < 4; ++k4) Ac[k4] = An[k4];
      cur ^= 1;
    }
  }

  // ---- epilogue: bias, silu^2, LN (in-place in acc), transpose, store ----
  float bia[8];
  #pragma unroll
  for (int n = 0; n < 8; ++n) bia[n] = bias[n * 16 + l15];

  float sum[4] = {0.f, 0.f, 0.f, 0.f};
  float ssq[4] = {0.f, 0.f, 0.f, 0.f};
  #pragma unroll
  for (int n = 0; n < 8; ++n) {
    #pragma unroll
    for (int j = 0; j < 4; ++j) {
      float t = silu_f(silu_f(acc[n][j] + bia[n]));
      acc[n][j] = t;              // reuse accumulator storage
      sum[j] += t;
      ssq[j] += t * t;
    }
  }
  #pragma unroll
  for (int off = 1; off < 16; off <<= 1) {
    #pragma unroll
    for (int j = 0; j < 4; ++j) {
      sum[j] += __shfl_xor(sum[j], off);
      ssq[j] += __shfl_xor(ssq[j], off);
    }
  }
  float mu[4], rs[4];
  #pragma unroll
  for (int j = 0; j < 4; ++j) {
    mu[j] = sum[j] * (1.0f / 128.0f);
    float var = ssq[j] * (1.0f / 128.0f) - mu[j] * mu[j];
    rs[j] = rsqrtf(var + 1e-5f);
  }
  float gam[8], bet[8];
  #pragma unroll
  for (int n = 0; n < 8; ++n) {
    gam[n] = gamma[n * 16 + l15];
    bet[n] = beta[n * 16 + l15];
  }

  // transpose through LDS overlay (per-wave 16x132 slice; wave-local sync)
  unsigned short* yw = &smem[0][0] + wid * (16 * 132);
  #pragma unroll
  for (int n = 0; n < 8; ++n) {
    #pragma unroll
    for (int j = 0; j < 4; ++j) {
      float y = (acc[n][j] - mu[j]) * rs[j] * gam[n] + bet[n];
      BF1 c; c.h = (__bf16)y;
      yw[(q * 4 + j) * 132 + n * 16 + l15] = c.s;
    }
  }
  asm volatile("s_waitcnt lgkmcnt(0)" ::: "memory");

  #pragma unroll
  for (int s = 0; s < 8; ++s) {
    int row16 = 2 * s + rhalf;
    int grow = wrow + row16;
    uint2 w = *reinterpret_cast<const uint2*>(&yw[row16 * 132 + l31 * 4]);
    if (grow < M) {
      const f32x4 r4 = *reinterpret_cast<const f32x4*>(resid + (size_t)grow * 128 + l31 * 4);
      f32x4 o4;
      o4.x = r4.x + bfu2f(w.x & 0xffffu);
      o4.y = r4.y + bfu2f(w.x >> 16);
      o4.z = r4.z + bfu2f(w.y & 0xffffu);
      o4.w = r4.w + bfu2f(w.y >> 16);
      __builtin_nontemporal_store(o4, reinterpret_cast<f32x4*>(outp + (size_t)grow * 128 + l31 * 4));
      if constexpr (AGGR == 3) {
        int prow = prank[grow];
        *reinterpret_cast<uint2*>((unsigned short*)aggr + (size_t)prow * 128 + l31 * 4) = w;
      } else if constexpr (AGGR == 2) {
        int idx = aggr_idx[grow];
        unsigned short* ar = (unsigned short*)aggr + (size_t)idx * 128 + l31 * 4;
        asm volatile("global_atomic_pk_add_bf16 %0, %1, off" :: "v"(ar), "v"(w.x) : "memory");
        asm volatile("global_atomic_pk_add_bf16 %0, %1, off" :: "v"(ar + 2), "v"(w.y) : "memory");
      } else if constexpr (AGGR == 1) {
        int idx = aggr_idx[grow];
        float* ar = (float*)aggr + (size_t)idx * 128 + l31 * 4;
        atomicAdd(ar + 0, bfu2f(w.x & 0xffffu));
        atomicAdd(ar + 1, bfu2f(w.x >> 16));
        atomicAdd(ar + 2, bfu2f(w.y & 0xffffu));
        atomicAdd(ar + 3, bfu2f(w.y >> 16));
      }
    }
  }
}

extern "C" void kernel_launch(void* const* d_in, const int* in_sizes, int n_in,
                              void* d_out, int out_size, void* d_ws, size_t ws_size,
                              hipStream_t stream) {
  const float* sender_x   = (const float*)d_in[0];
  const float* receiver_x = (const float*)d_in[1];
  const int*   edge_index = (const int*)d_in[2];
  const float* edge_attr  = (const float*)d_in[3];
  const float* We  = (const float*)d_in[4];
  const float* be  = (const float*)d_in[5];
  const float* ge  = (const float*)d_in[6];
  const float* bbe = (const float*)d_in[7];
  const float* Wn  = (const float*)d_in[8];
  const float* bn  = (const float*)d_in[9];
  const float* gn  = (const float*)d_in[10];
  const float* bbn = (const float*)d_in[11];
  const float* Ws  = (const float*)d_in[12];
  const float* bs  = (const float*)d_in[13];
  const float* gs  = (const float*)d_in[14];
  const float* bbs = (const float*)d_in[15];

  const int D  = 128;
  const int NS = in_sizes[0] / D;
  const int NR = in_sizes[1] / D;
  const int E  = in_sizes[2] / 2;

  const int* src = edge_index;
  const int* dst = edge_index + E;

  float* out          = (float*)d_out;
  float* sender_out   = out;
  float* receiver_out = out + (size_t)NS * D;
  float* edge_out     = out + (size_t)(NS + NR) * D;

  const size_t welems = 6 * 16384;  // 98304, same footprint as before
  unsigned short* We_b = (unsigned short*)d_ws;          // panels 0..2
  unsigned short* Wn_b = We_b + 3 * 16384;               // panels 3..4
  unsigned short* Ws_b = We_b + 5 * 16384;               // panel 5
  unsigned short* sender_b   = We_b + welems;
  unsigned short* receiver_b = sender_b + (size_t)NS * D;
  unsigned short* aggr_b     = receiver_b + (size_t)NR * D;
  unsigned short* P_b        = aggr_b + (size_t)NR * D;
  int* counts    = (int*)(P_b + (size_t)E * D);
  int* pre       = counts + NR;
  int* offs      = pre + NR;
  int* cursor    = offs + NR;
  int* blockSums = cursor + NR;
  int* rank      = blockSums + 512;

  const int nScanBlocks = (NR + 1023) / 1024;
  const size_t needCSR = 2 * (welems + (size_t)(NS + 2 * NR) * D + (size_t)E * D)
                       + 4 * (4 * (size_t)NR + 512 + (size_t)E);
  const size_t needA = (welems + (size_t)(NS + 2 * NR) * D) * 2;
  const size_t needB = (welems + (size_t)NR * D) * 2;
  unsigned short* aggrB = We_b + welems;

  int tier;
  if (ws_size >= needCSR && nScanBlocks <= 512) tier = 0;
  else if (ws_size >= needA) tier = 1;
  else if (ws_size >= needB) tier = 2;
  else tier = 3;

  cvt_weights_kernel<<<(int)((welems + 255) / 256), 256, 0, stream>>>(We, Wn, Ws, We_b);

  const int gridE = (E + 127) / 128;
  const int gridR = (NR + 127) / 128;
  const int gridS = (NS + 127) / 128;
  const int n8s = NS * D / 8, n8r = NR * D / 8;

  if (tier == 0) {
    cvt_rows_kernel<<<(n8s + 255) / 256, 256, 0, stream>>>(sender_x, sender_b, n8s);
    cvt_rows_kernel<<<(n8r + 255) / 256, 256, 0, stream>>>(receiver_x, receiver_b, n8r);

    (void)hipMemsetAsync(counts, 0, (size_t)NR * 4, stream);
    hist_kernel<<<(E + 255) / 256, 256, 0, stream>>>(dst, counts, E);
    scan1_kernel<<<nScanBlocks, 256, 0, stream>>>(counts, pre, blockSums, NR);
    scan2_kernel<<<1, 512, 0, stream>>>(blockSums, nScanBlocks);
    scan3_kernel<<<(NR + 255) / 256, 256, 0, stream>>>(pre, blockSums, offs, cursor, NR);
    scatter_kernel<<<(E + 255) / 256, 256, 0, stream>>>(dst, cursor, rank, E);

    mlp_v8_kernel<384, 3, true, true><<<gridE, 512, 0, stream>>>(
        sender_b, src, receiver_b, dst, edge_attr,
        We_b, be, ge, bbe, edge_attr, edge_out, P_b, nullptr, rank, E);

    agg_kernel<<<(NR + 7) / 8, 256, 0, stream>>>(P_b, offs, counts, aggr_b, NR);

    mlp_v8_kernel<256, 0, true, true><<<gridR, 512, 0, stream>>>(
        receiver_b, nullptr, aggr_b, nullptr, nullptr,
        Wn_b, bn, gn, bbn, receiver_x, receiver_out, nullptr, nullptr, nullptr, NR);

    mlp_v8_kernel<128, 0, true, false><<<gridS, 512, 0, stream>>>(
        sender_b, nullptr, nullptr, nullptr, nullptr,
        Ws_b, bs, gs, bbs, sender_x, sender_out, nullptr, nullptr, nullptr, NS);
  } else if (tier == 1) {
    cvt_rows_kernel<<<(n8s + 255) / 256, 256, 0, stream>>>(sender_x, sender_b, n8s);
    cvt_rows_kernel<<<(n8r + 255) / 256, 256, 0, stream>>>(receiver_x, receiver_b, n8r);
    (void)hipMemsetAsync(aggr_b, 0, (size_t)NR * D * 2, stream);

    mlp_v8_kernel<384, 2, true, true><<<gridE, 512, 0, stream>>>(
        sender_b, src, receiver_b, dst, edge_attr,
        We_b, be, ge, bbe, edge_attr, edge_out, aggr_b, dst, nullptr, E);

    mlp_v8_kernel<256, 0, true, true><<<gridR, 512, 0, stream>>>(
        receiver_b, nullptr, aggr_b, nullptr, nullptr,
        Wn_b, bn, gn, bbn, receiver_x, receiver_out, nullptr, nullptr, nullptr, NR);

    mlp_v8_kernel<128, 0, true, false><<<gridS, 512, 0, stream>>>(
        sender_b, nullptr, nullptr, nullptr, nullptr,
        Ws_b, bs, gs, bbs, sender_x, sender_out, nullptr, nullptr, nullptr, NS);
  } else if (tier == 2) {
    (void)hipMemsetAsync(aggrB, 0, (size_t)NR * D * 2, stream);

    mlp_v8_kernel<384, 2, false, false><<<gridE, 512, 0, stream>>>(
        sender_x, src, receiver_x, dst, edge_attr,
        We_b, be, ge, bbe, edge_attr, edge_out, aggrB, dst, nullptr, E);

    mlp_v8_kernel<256, 0, false, true><<<gridR, 512, 0, stream>>>(
        receiver_x, nullptr, aggrB, nullptr, nullptr,
        Wn_b, bn, gn, bbn, receiver_x, receiver_out, nullptr, nullptr, nullptr, NR);

    mlp_v8_kernel<128, 0, false, false><<<gridS, 512, 0, stream>>>(
        sender_x, nullptr, nullptr, nullptr, nullptr,
        Ws_b, bs, gs, bbs, sender_x, sender_out, nullptr, nullptr, nullptr, NS);
  } else {
    (void)hipMemsetAsync(receiver_out, 0, (size_t)NR * D * sizeof(float), stream);

    mlp_v8_kernel<384, 1, false, false><<<gridE, 512, 0, stream>>>(
        sender_x, src, receiver_x, dst, edge_attr,
        We_b, be, ge, bbe, edge_attr, edge_out, receiver_out, dst, nullptr, E);

    mlp_v8_kernel<256, 0, false, false><<<gridR, 512, 0, stream>>>(
        receiver_x, nullptr, receiver_out, nullptr, nullptr,
        Wn_b, bn, gn, bbn, receiver_x, receiver_out, nullptr, nullptr, nullptr, NR);

    mlp_v8_kernel<128, 0, false, false><<<gridS, 512, 0, stream>>>(
        sender_x, nullptr, nullptr, nullptr, nullptr,
        Ws_b, bs, gs, bbs, sender_x, sender_out, nullptr, nullptr, nullptr, NS);
  }
}

// Round 9
// 454.458 us; speedup vs baseline: 1.6383x; 1.0156x over previous
//
#include <hip/hip_runtime.h>
#include <stdint.h>

// ---------------------------------------------------------------------------
// GCastHeterocoder round 9: v9 MLP kernel = v8 + (a) ALL-segment A-gather
// prefetch at kernel start (latency paid once at the first barrier), (b) full
// 4-bit row swizzle on the B image (even bank spread), (c) 3 barriers instead
// of 4 (epilogue transpose lands in the buffer the last segment doesn't read).
// Fused prep kernel converts weights+sender+receiver in one launch.
// ---------------------------------------------------------------------------

typedef __bf16 bf16x8 __attribute__((ext_vector_type(8)));
typedef float  f32x4  __attribute__((ext_vector_type(4)));

union U16B { uint4 u; bf16x8 v; };
union BFPK { __bf16 h[2]; unsigned int u; };
union BF1  { __bf16 h; unsigned short s; };

__device__ __forceinline__ float silu_f(float x) {
  return x * __builtin_amdgcn_rcpf(1.0f + __expf(-x));
}
__device__ __forceinline__ float bfu2f(unsigned int lo16) {
  return __uint_as_float(lo16 << 16);
}
__device__ __forceinline__ bf16x8 cvt8(float4 a, float4 b) {
  bf16x8 r;
  r[0] = (__bf16)a.x; r[1] = (__bf16)a.y; r[2] = (__bf16)a.z; r[3] = (__bf16)a.w;
  r[4] = (__bf16)b.x; r[5] = (__bf16)b.y; r[6] = (__bf16)b.z; r[7] = (__bf16)b.w;
  return r;
}

// ---------------- fused prep: weights (swizzled image) + feature rows ------
// Weight image: 6 panels [128 r][128 c]; row r byte b holds W[r][(b^((r&15)<<4))/2].
__global__ void prep_kernel(const float* __restrict__ We,
                            const float* __restrict__ Wn,
                            const float* __restrict__ Ws,
                            unsigned short* __restrict__ wimg,
                            const float* __restrict__ sx,
                            unsigned short* __restrict__ sb,
                            const float* __restrict__ rx,
                            unsigned short* __restrict__ rb,
                            int n8s, int n8r) {
  int i = blockIdx.x * 256 + threadIdx.x;
  if (i < 6 * 16384) {
    int panel = i >> 14;
    int r = (i >> 7) & 127;
    int csw = i & 127;
    int c_or = ((csw * 2) ^ ((r & 15) << 4)) >> 1;
    float f;
    if (panel < 3)      f = We[r * 384 + panel * 128 + c_or];
    else if (panel < 5) f = Wn[r * 256 + (panel - 3) * 128 + c_or];
    else                f = Ws[r * 128 + c_or];
    BF1 c; c.h = (__bf16)f;
    wimg[i] = c.s;
    return;
  }
  int j = i - 6 * 16384;
  const float* in; unsigned short* out; int idx;
  if (j < n8s) { in = sx; out = sb; idx = j; }
  else if (j < n8s + n8r) { in = rx; out = rb; idx = j - n8s; }
  else return;
  float4 a = reinterpret_cast<const float4*>(in)[2 * idx];
  float4 b = reinterpret_cast<const float4*>(in)[2 * idx + 1];
  U16B r8; r8.v = cvt8(a, b);
  reinterpret_cast<uint4*>(out)[idx] = r8.u;
}

// ---------------- CSR build ----------------
__global__ void hist_kernel(const int* __restrict__ dst, int* __restrict__ counts, int E) {
  int i = blockIdx.x * 256 + threadIdx.x;
  if (i < E) atomicAdd(&counts[dst[i]], 1);
}

__global__ void scan1_kernel(const int* __restrict__ counts, int* __restrict__ pre,
                             int* __restrict__ blockSums, int n) {
  __shared__ int sh[256];
  const int t = threadIdx.x;
  const int base = blockIdx.x * 1024 + t * 4;
  int c0 = (base + 0 < n) ? counts[base + 0] : 0;
  int c1 = (base + 1 < n) ? counts[base + 1] : 0;
  int c2 = (base + 2 < n) ? counts[base + 2] : 0;
  int c3 = (base + 3 < n) ? counts[base + 3] : 0;
  int tot = c0 + c1 + c2 + c3;
  sh[t] = tot;
  __syncthreads();
  #pragma unroll
  for (int off = 1; off < 256; off <<= 1) {
    int v = (t >= off) ? sh[t - off] : 0;
    __syncthreads();
    sh[t] += v;
    __syncthreads();
  }
  int excl = sh[t] - tot;
  if (base + 0 < n) pre[base + 0] = excl;
  if (base + 1 < n) pre[base + 1] = excl + c0;
  if (base + 2 < n) pre[base + 2] = excl + c0 + c1;
  if (base + 3 < n) pre[base + 3] = excl + c0 + c1 + c2;
  if (t == 255) blockSums[blockIdx.x] = sh[255];
}

__global__ void scan2_kernel(int* __restrict__ blockSums, int nb) {
  __shared__ int sh[512];
  const int t = threadIdx.x;
  int v = (t < nb) ? blockSums[t] : 0;
  sh[t] = v;
  __syncthreads();
  #pragma unroll
  for (int off = 1; off < 512; off <<= 1) {
    int u = (t >= off) ? sh[t - off] : 0;
    __syncthreads();
    sh[t] += u;
    __syncthreads();
  }
  if (t < nb) blockSums[t] = sh[t] - v;
}

__global__ void scan3_kernel(const int* __restrict__ pre, const int* __restrict__ blockSums,
                             int* __restrict__ offs, int* __restrict__ cursor, int n) {
  int i = blockIdx.x * 256 + threadIdx.x;
  if (i >= n) return;
  int o = pre[i] + blockSums[i >> 10];
  offs[i] = o;
  cursor[i] = o;
}

__global__ void scatter_kernel(const int* __restrict__ dst, int* __restrict__ cursor,
                               int* __restrict__ rank, int E) {
  int i = blockIdx.x * 256 + threadIdx.x;
  if (i < E) {
    int p = atomicAdd(&cursor[dst[i]], 1);
    rank[i] = p;
  }
}

// segment sum over CONTIGUOUS P rows [offs[r], offs[r]+counts[r])
__global__ __launch_bounds__(256) void agg_kernel(
    const unsigned short* __restrict__ P,
    const int* __restrict__ offs, const int* __restrict__ counts,
    unsigned short* __restrict__ aggr, int NR) {
  const int l = threadIdx.x & 31;
  const int g0 = (blockIdx.x * 256 + threadIdx.x) >> 5;
  if (g0 >= NR) return;
  int beg = offs[g0];
  int cnt = counts[g0];
  float s0 = 0.f, s1 = 0.f, s2 = 0.f, s3 = 0.f;
  const unsigned short* p = P + (size_t)beg * 128 + l * 4;
  for (int k = 0; k < cnt; ++k) {
    uint2 w = *reinterpret_cast<const uint2*>(p);
    p += 128;
    s0 += bfu2f(w.x & 0xffffu);
    s1 += bfu2f(w.x >> 16);
    s2 += bfu2f(w.y & 0xffffu);
    s3 += bfu2f(w.y >> 16);
  }
  BFPK a, b;
  a.h[0] = (__bf16)s0; a.h[1] = (__bf16)s1;
  b.h[0] = (__bf16)s2; b.h[1] = (__bf16)s3;
  uint2 o; o.x = a.u; o.y = b.u;
  *reinterpret_cast<uint2*>(aggr + (size_t)g0 * 128 + l * 4) = o;
}

// ---------------------------------------------------------------------------
// v9: bf16 s0/s1 features, fp32 s2. All A-gathers issued at kernel start.
// 512 thr / 8 waves, 128 rows/block (wave = 16 rows x 128 ch).
// AGGR: 0=none, 2=pk bf16 atomics, 3=P row at prank[grow].
// ---------------------------------------------------------------------------
template <int KDIM, int AGGR>
__global__ __launch_bounds__(512, 4) void mlp_v9_kernel(
    const unsigned short* __restrict__ s0, const int* __restrict__ i0,
    const unsigned short* __restrict__ s1, const int* __restrict__ i1,
    const float* __restrict__ s2,
    const unsigned short* __restrict__ Wb,   // swizzled image, NSEG panels
    const float* __restrict__ bias, const float* __restrict__ gamma,
    const float* __restrict__ beta,
    const float* __restrict__ resid,
    float* __restrict__ outp,
    void* aggr, const int* __restrict__ aggr_idx,
    const int* __restrict__ prank,
    int M) {
  constexpr int NSEG = KDIM / 128;
  __shared__ __align__(16) unsigned short smem[2][16384];  // 64 KB dbuf

  const int tid = threadIdx.x;
  const int wid = tid >> 6;
  const int lane = tid & 63;
  const int l15 = lane & 15;
  const int q = lane >> 4;
  const int l31 = lane & 31;
  const int rhalf = lane >> 5;
  const int wrow = blockIdx.x * 128 + wid * 16;
  const int xm = l15 << 3;   // ushort-unit XOR for full 4-bit row swizzle

  int rr = wrow + l15;
  if (rr >= M) rr = M - 1;  // clamp tail; stores masked later
  const unsigned short* p0 = s0 + (size_t)(i0 ? i0[rr] : rr) * 128;
  const unsigned short* p1 = nullptr;
  const float* p2 = nullptr;
  if constexpr (KDIM >= 256) p1 = s1 + (size_t)(i1 ? i1[rr] : rr) * 128;
  if constexpr (KDIM >= 384) p2 = s2 + (size_t)rr * 128;

  // stage one 32 KB B panel via global_load_lds
  auto stageB = [&](int seg, int buf) {
    const unsigned short* g = Wb + seg * 16384 + wid * 2048 + lane * 8;
    unsigned short* l = &smem[buf][wid * 2048];
    #pragma unroll
    for (int u = 0; u < 4; ++u) {
      __builtin_amdgcn_global_load_lds(
          (const __attribute__((address_space(1))) unsigned int*)(g + u * 512),
          (__attribute__((address_space(3))) unsigned int*)(l + u * 512),
          16, 0, 0);
    }
  };

  // ---- issue everything up front: B0 (+B1) stages + ALL A gathers ----
  stageB(0, 0);
  if constexpr (NSEG > 1) stageB(1, 1);

  U16B A0[4], A1[4];
  float4 A2r[8];
  #pragma unroll
  for (int k4 = 0; k4 < 4; ++k4) {
    A0[k4].u = *reinterpret_cast<const uint4*>(p0 + k4 * 32 + q * 8);
    if constexpr (KDIM >= 256)
      A1[k4].u = *reinterpret_cast<const uint4*>(p1 + k4 * 32 + q * 8);
    if constexpr (KDIM >= 384) {
      A2r[2 * k4]     = reinterpret_cast<const float4*>(p2 + k4 * 32 + q * 8)[0];
      A2r[2 * k4 + 1] = reinterpret_cast<const float4*>(p2 + k4 * 32 + q * 8)[1];
    }
  }
  __builtin_amdgcn_sched_barrier(0);   // pin: no sinking of the gathers
  __syncthreads();                     // #1: A + B0 (+B1) all landed

  f32x4 acc[8] = {};

  auto mfmaSeg = [&](int buf, const U16B (&A)[4]) {
    #pragma unroll
    for (int k4 = 0; k4 < 4; ++k4) {
      #pragma unroll
      for (int n = 0; n < 8; ++n) {
        U16B b;
        b.u = *reinterpret_cast<const uint4*>(
            &smem[buf][(n * 16 + l15) * 128 + ((k4 * 32 + q * 8) ^ xm)]);
        acc[n] = __builtin_amdgcn_mfma_f32_16x16x32_bf16(A[k4].v, b.v, acc[n], 0, 0, 0);
      }
    }
  };

  mfmaSeg(0, A0);                      // seg0 from buf0
  if constexpr (NSEG >= 2) {
    __syncthreads();                   // #2: buf0 free
    if constexpr (NSEG >= 3) stageB(2, 0);
    mfmaSeg(1, A1);                    // seg1 from buf1
    if constexpr (NSEG >= 3) {
      __syncthreads();                 // #3: B2 landed, buf1 free
      U16B A2[4];
      #pragma unroll
      for (int k4 = 0; k4 < 4; ++k4) A2[k4].v = cvt8(A2r[2 * k4], A2r[2 * k4 + 1]);
      mfmaSeg(0, A2);                  // seg2 from buf0
    }
  }

  // ---- epilogue: yT lands in the buffer the LAST segment does not read ----
  // NSEG==2 -> last reads buf1 -> yT in buf0 (freed by barrier #2).
  // NSEG==1/3 -> last reads buf0 -> yT in buf1 (idle / freed by barrier #3).
  unsigned short* yw = (NSEG == 2 ? &smem[0][0] : &smem[1][0]) + wid * (16 * 132);

  float bia[8];
  #pragma unroll
  for (int n = 0; n < 8; ++n) bia[n] = bias[n * 16 + l15];

  float sum[4] = {0.f, 0.f, 0.f, 0.f};
  float ssq[4] = {0.f, 0.f, 0.f, 0.f};
  #pragma unroll
  for (int n = 0; n < 8; ++n) {
    #pragma unroll
    for (int j = 0; j < 4; ++j) {
      float t = silu_f(silu_f(acc[n][j] + bia[n]));
      acc[n][j] = t;
      sum[j] += t;
      ssq[j] += t * t;
    }
  }
  #pragma unroll
  for (int off = 1; off < 16; off <<= 1) {
    #pragma unroll
    for (int j = 0; j < 4; ++j) {
      sum[j] += __shfl_xor(sum[j], off);
      ssq[j] += __shfl_xor(ssq[j], off);
    }
  }
  float mu[4], rs[4];
  #pragma unroll
  for (int j = 0; j < 4; ++j) {
    mu[j] = sum[j] * (1.0f / 128.0f);
    float var = ssq[j] * (1.0f / 128.0f) - mu[j] * mu[j];
    rs[j] = rsqrtf(var + 1e-5f);
  }
  float gam[8], bet[8];
  #pragma unroll
  for (int n = 0; n < 8; ++n) {
    gam[n] = gamma[n * 16 + l15];
    bet[n] = beta[n * 16 + l15];
  }

  #pragma unroll
  for (int n = 0; n < 8; ++n) {
    #pragma unroll
    for (int j = 0; j < 4; ++j) {
      float y = (acc[n][j] - mu[j]) * rs[j] * gam[n] + bet[n];
      BF1 c; c.h = (__bf16)y;
      yw[(q * 4 + j) * 132 + n * 16 + l15] = c.s;
    }
  }
  asm volatile("s_waitcnt lgkmcnt(0)" ::: "memory");

  #pragma unroll
  for (int s = 0; s < 8; ++s) {
    int row16 = 2 * s + rhalf;
    int grow = wrow + row16;
    uint2 w = *reinterpret_cast<const uint2*>(&yw[row16 * 132 + l31 * 4]);
    if (grow < M) {
      const f32x4 r4 = *reinterpret_cast<const f32x4*>(resid + (size_t)grow * 128 + l31 * 4);
      f32x4 o4;
      o4.x = r4.x + bfu2f(w.x & 0xffffu);
      o4.y = r4.y + bfu2f(w.x >> 16);
      o4.z = r4.z + bfu2f(w.y & 0xffffu);
      o4.w = r4.w + bfu2f(w.y >> 16);
      __builtin_nontemporal_store(o4, reinterpret_cast<f32x4*>(outp + (size_t)grow * 128 + l31 * 4));
      if constexpr (AGGR == 3) {
        int prow = prank[grow];
        *reinterpret_cast<uint2*>((unsigned short*)aggr + (size_t)prow * 128 + l31 * 4) = w;
      } else if constexpr (AGGR == 2) {
        int idx = aggr_idx[grow];
        unsigned short* ar = (unsigned short*)aggr + (size_t)idx * 128 + l31 * 4;
        asm volatile("global_atomic_pk_add_bf16 %0, %1, off" :: "v"(ar), "v"(w.x) : "memory");
        asm volatile("global_atomic_pk_add_bf16 %0, %1, off" :: "v"(ar + 2), "v"(w.y) : "memory");
      }
    }
  }
}

// ---------------------------------------------------------------------------
// fallback kernel (fp32 features, fp32 atomics) for small-ws tiers.
// ---------------------------------------------------------------------------
template <int KDIM>
__global__ __launch_bounds__(512, 4) void mlp_fb_kernel(
    const float* __restrict__ s0, const int* __restrict__ i0,
    const float* __restrict__ s1, const int* __restrict__ i1,
    const float* __restrict__ s2,
    const unsigned short* __restrict__ Wb,
    const float* __restrict__ bias, const float* __restrict__ gamma,
    const float* __restrict__ beta,
    const float* __restrict__ resid,
    float* __restrict__ outp,
    float* aggr, const int* __restrict__ aggr_idx,
    int M) {
  constexpr int NSEG = KDIM / 128;
  __shared__ __align__(16) unsigned short smem[2][16384];
  const int tid = threadIdx.x;
  const int wid = tid >> 6;
  const int lane = tid & 63;
  const int l15 = lane & 15;
  const int q = lane >> 4;
  const int l31 = lane & 31;
  const int rhalf = lane >> 5;
  const int wrow = blockIdx.x * 128 + wid * 16;
  const int xm = l15 << 3;

  int rr = wrow + l15;
  if (rr >= M) rr = M - 1;
  const float* p0 = s0 + (size_t)(i0 ? i0[rr] : rr) * 128;
  const float* p1 = (KDIM >= 256) ? (s1 + (size_t)(i1 ? i1[rr] : rr) * 128) : nullptr;
  const float* p2 = (KDIM >= 384) ? (s2 + (size_t)rr * 128) : nullptr;

  auto stageB = [&](int seg, int buf) {
    const unsigned short* g = Wb + seg * 16384 + wid * 2048 + lane * 8;
    unsigned short* l = &smem[buf][wid * 2048];
    #pragma unroll
    for (int u = 0; u < 4; ++u) {
      __builtin_amdgcn_global_load_lds(
          (const __attribute__((address_space(1))) unsigned int*)(g + u * 512),
          (__attribute__((address_space(3))) unsigned int*)(l + u * 512),
          16, 0, 0);
    }
  };

  stageB(0, 0);
  f32x4 acc[8] = {};
  __syncthreads();
  int cur = 0;
  #pragma unroll
  for (int seg = 0; seg < NSEG; ++seg) {
    if (seg + 1 < NSEG) stageB(seg + 1, cur ^ 1);
    const float* base = (seg == 0) ? p0 : ((seg == 1) ? p1 : p2);
    #pragma unroll
    for (int k4 = 0; k4 < 4; ++k4) {
      const float4* pp = reinterpret_cast<const float4*>(base + k4 * 32 + q * 8);
      U16B a; a.v = cvt8(pp[0], pp[1]);
      #pragma unroll
      for (int n = 0; n < 8; ++n) {
        U16B b;
        b.u = *reinterpret_cast<const uint4*>(
            &smem[cur][(n * 16 + l15) * 128 + ((k4 * 32 + q * 8) ^ xm)]);
        acc[n] = __builtin_amdgcn_mfma_f32_16x16x32_bf16(a.v, b.v, acc[n], 0, 0, 0);
      }
    }
    __syncthreads();
    if (seg + 1 < NSEG) cur ^= 1;
  }

  unsigned short* yw = &smem[0][0] + wid * (16 * 132);
  float bia[8];
  #pragma unroll
  for (int n = 0; n < 8; ++n) bia[n] = bias[n * 16 + l15];
  float sum[4] = {0.f, 0.f, 0.f, 0.f}, ssq[4] = {0.f, 0.f, 0.f, 0.f};
  #pragma unroll
  for (int n = 0; n < 8; ++n)
    #pragma unroll
    for (int j = 0; j < 4; ++j) {
      float t = silu_f(silu_f(acc[n][j] + bia[n]));
      acc[n][j] = t; sum[j] += t; ssq[j] += t * t;
    }
  #pragma unroll
  for (int off = 1; off < 16; off <<= 1)
    #pragma unroll
    for (int j = 0; j < 4; ++j) {
      sum[j] += __shfl_xor(sum[j], off);
      ssq[j] += __shfl_xor(ssq[j], off);
    }
  float mu[4], rs[4];
  #pragma unroll
  for (int j = 0; j < 4; ++j) {
    mu[j] = sum[j] * (1.0f / 128.0f);
    float var = ssq[j] * (1.0f / 128.0f) - mu[j] * mu[j];
    rs[j] = rsqrtf(var + 1e-5f);
  }
  float gam[8], bet[8];
  #pragma unroll
  for (int n = 0; n < 8; ++n) { gam[n] = gamma[n * 16 + l15]; bet[n] = beta[n * 16 + l15]; }
  #pragma unroll
  for (int n = 0; n < 8; ++n)
    #pragma unroll
    for (int j = 0; j < 4; ++j) {
      float y = (acc[n][j] - mu[j]) * rs[j] * gam[n] + bet[n];
      BF1 c; c.h = (__bf16)y;
      yw[(q * 4 + j) * 132 + n * 16 + l15] = c.s;
    }
  asm volatile("s_waitcnt lgkmcnt(0)" ::: "memory");
  #pragma unroll
  for (int s = 0; s < 8; ++s) {
    int row16 = 2 * s + rhalf;
    int grow = wrow + row16;
    uint2 w = *reinterpret_cast<const uint2*>(&yw[row16 * 132 + l31 * 4]);
    if (grow < M) {
      const f32x4 r4 = *reinterpret_cast<const f32x4*>(resid + (size_t)grow * 128 + l31 * 4);
      f32x4 o4;
      o4.x = r4.x + bfu2f(w.x & 0xffffu);
      o4.y = r4.y + bfu2f(w.x >> 16);
      o4.z = r4.z + bfu2f(w.y & 0xffffu);
      o4.w = r4.w + bfu2f(w.y >> 16);
      __builtin_nontemporal_store(o4, reinterpret_cast<f32x4*>(outp + (size_t)grow * 128 + l31 * 4));
      if (aggr) {
        int idx = aggr_idx[grow];
        float* ar = aggr + (size_t)idx * 128 + l31 * 4;
        atomicAdd(ar + 0, bfu2f(w.x & 0xffffu));
        atomicAdd(ar + 1, bfu2f(w.x >> 16));
        atomicAdd(ar + 2, bfu2f(w.y & 0xffffu));
        atomicAdd(ar + 3, bfu2f(w.y >> 16));
      }
    }
  }
}

extern "C" void kernel_launch(void* const* d_in, const int* in_sizes, int n_in,
                              void* d_out, int out_size, void* d_ws, size_t ws_size,
                              hipStream_t stream) {
  const float* sender_x   = (const float*)d_in[0];
  const float* receiver_x = (const float*)d_in[1];
  const int*   edge_index = (const int*)d_in[2];
  const float* edge_attr  = (const float*)d_in[3];
  const float* We  = (const float*)d_in[4];
  const float* be  = (const float*)d_in[5];
  const float* ge  = (const float*)d_in[6];
  const float* bbe = (const float*)d_in[7];
  const float* Wn  = (const float*)d_in[8];
  const float* bn  = (const float*)d_in[9];
  const float* gn  = (const float*)d_in[10];
  const float* bbn = (const float*)d_in[11];
  const float* Ws  = (const float*)d_in[12];
  const float* bs  = (const float*)d_in[13];
  const float* gs  = (const float*)d_in[14];
  const float* bbs = (const float*)d_in[15];

  const int D  = 128;
  const int NS = in_sizes[0] / D;
  const int NR = in_sizes[1] / D;
  const int E  = in_sizes[2] / 2;

  const int* src = edge_index;
  const int* dst = edge_index + E;

  float* out          = (float*)d_out;
  float* sender_out   = out;
  float* receiver_out = out + (size_t)NS * D;
  float* edge_out     = out + (size_t)(NS + NR) * D;

  const size_t welems = 6 * 16384;
  unsigned short* We_b = (unsigned short*)d_ws;          // panels 0..2
  unsigned short* Wn_b = We_b + 3 * 16384;               // panels 3..4
  unsigned short* Ws_b = We_b + 5 * 16384;               // panel 5
  unsigned short* sender_b   = We_b + welems;
  unsigned short* receiver_b = sender_b + (size_t)NS * D;
  unsigned short* aggr_b     = receiver_b + (size_t)NR * D;
  unsigned short* P_b        = aggr_b + (size_t)NR * D;
  int* counts    = (int*)(P_b + (size_t)E * D);
  int* pre       = counts + NR;
  int* offs      = pre + NR;
  int* cursor    = offs + NR;
  int* blockSums = cursor + NR;
  int* rank      = blockSums + 512;

  const int nScanBlocks = (NR + 1023) / 1024;
  const size_t needCSR = 2 * (welems + (size_t)(NS + 2 * NR) * D + (size_t)E * D)
                       + 4 * (4 * (size_t)NR + 512 + (size_t)E);
  const size_t needA = (welems + (size_t)(NS + 2 * NR) * D) * 2;

  int tier;
  if (ws_size >= needCSR && nScanBlocks <= 512) tier = 0;
  else if (ws_size >= needA) tier = 1;
  else tier = 2;

  const int gridE = (E + 127) / 128;
  const int gridR = (NR + 127) / 128;
  const int gridS = (NS + 127) / 128;
  const int n8s = NS * D / 8, n8r = NR * D / 8;

  if (tier <= 1) {
    // fused prep: weight image + sender/receiver bf16 rows
    const int prepItems = (int)welems + n8s + n8r;
    prep_kernel<<<(prepItems + 255) / 256, 256, 0, stream>>>(
        We, Wn, Ws, We_b, sender_x, sender_b, receiver_x, receiver_b, n8s, n8r);
  } else {
    prep_kernel<<<(int)((welems + 255) / 256), 256, 0, stream>>>(
        We, Wn, Ws, We_b, nullptr, nullptr, nullptr, nullptr, 0, 0);
  }

  if (tier == 0) {
    (void)hipMemsetAsync(counts, 0, (size_t)NR * 4, stream);
    hist_kernel<<<(E + 255) / 256, 256, 0, stream>>>(dst, counts, E);
    scan1_kernel<<<nScanBlocks, 256, 0, stream>>>(counts, pre, blockSums, NR);
    scan2_kernel<<<1, 512, 0, stream>>>(blockSums, nScanBlocks);
    scan3_kernel<<<(NR + 255) / 256, 256, 0, stream>>>(pre, blockSums, offs, cursor, NR);
    scatter_kernel<<<(E + 255) / 256, 256, 0, stream>>>(dst, cursor, rank, E);

    mlp_v9_kernel<384, 3><<<gridE, 512, 0, stream>>>(
        sender_b, src, receiver_b, dst, edge_attr,
        We_b, be, ge, bbe, edge_attr, edge_out, P_b, nullptr, rank, E);

    agg_kernel<<<(NR + 7) / 8, 256, 0, stream>>>(P_b, offs, counts, aggr_b, NR);

    mlp_v9_kernel<256, 0><<<gridR, 512, 0, stream>>>(
        receiver_b, nullptr, aggr_b, nullptr, nullptr,
        Wn_b, bn, gn, bbn, receiver_x, receiver_out, nullptr, nullptr, nullptr, NR);

    mlp_v9_kernel<128, 0><<<gridS, 512, 0, stream>>>(
        sender_b, nullptr, nullptr, nullptr, nullptr,
        Ws_b, bs, gs, bbs, sender_x, sender_out, nullptr, nullptr, nullptr, NS);
  } else if (tier == 1) {
    (void)hipMemsetAsync(aggr_b, 0, (size_t)NR * D * 2, stream);

    mlp_v9_kernel<384, 2><<<gridE, 512, 0, stream>>>(
        sender_b, src, receiver_b, dst, edge_attr,
        We_b, be, ge, bbe, edge_attr, edge_out, aggr_b, dst, nullptr, E);

    mlp_v9_kernel<256, 0><<<gridR, 512, 0, stream>>>(
        receiver_b, nullptr, aggr_b, nullptr, nullptr,
        Wn_b, bn, gn, bbn, receiver_x, receiver_out, nullptr, nullptr, nullptr, NR);

    mlp_v9_kernel<128, 0><<<gridS, 512, 0, stream>>>(
        sender_b, nullptr, nullptr, nullptr, nullptr,
        Ws_b, bs, gs, bbs, sender_x, sender_out, nullptr, nullptr, nullptr, NS);
  } else {
    (void)hipMemsetAsync(receiver_out, 0, (size_t)NR * D * sizeof(float), stream);

    mlp_fb_kernel<384><<<gridE, 512, 0, stream>>>(
        sender_x, src, receiver_x, dst, edge_attr,
        We_b, be, ge, bbe, edge_attr, edge_out, receiver_out, dst, E);

    mlp_fb_kernel<256><<<gridR, 512, 0, stream>>>(
        receiver_x, nullptr, receiver_out, nullptr, nullptr,
        Wn_b, bn, gn, bbn, receiver_x, receiver_out, nullptr, nullptr, NR);

    mlp_fb_kernel<128><<<gridS, 512, 0, stream>>>(
        sender_x, nullptr, nullptr, nullptr, nullptr,
        Ws_b, bs, gs, bbs, sender_x, sender_out, nullptr, nullptr, NS);
  }
}

// Round 10
// 450.023 us; speedup vs baseline: 1.6545x; 1.0099x over previous
//
#include <hip/hip_runtime.h>
#include <stdint.h>

// ---------------------------------------------------------------------------
// GCastHeterocoder round 10: single 32KB B-buffer (LDS 64->32KB) + 2-pass
// in-buffer epilogue transpose + launch_bounds(512,6) => 3 blocks/CU (75%
// occupancy target). One-segment-ahead A prefetch. hist fused into prep.
// CSR aggregation with rank-remapped sequential P.
// ---------------------------------------------------------------------------

typedef __bf16 bf16x8 __attribute__((ext_vector_type(8)));
typedef float  f32x4  __attribute__((ext_vector_type(4)));

union U16B { uint4 u; bf16x8 v; };
union BFPK { __bf16 h[2]; unsigned int u; };
union BF1  { __bf16 h; unsigned short s; };

__device__ __forceinline__ float silu_f(float x) {
  return x * __builtin_amdgcn_rcpf(1.0f + __expf(-x));
}
__device__ __forceinline__ float bfu2f(unsigned int lo16) {
  return __uint_as_float(lo16 << 16);
}
__device__ __forceinline__ bf16x8 cvt8(float4 a, float4 b) {
  bf16x8 r;
  r[0] = (__bf16)a.x; r[1] = (__bf16)a.y; r[2] = (__bf16)a.z; r[3] = (__bf16)a.w;
  r[4] = (__bf16)b.x; r[5] = (__bf16)b.y; r[6] = (__bf16)b.z; r[7] = (__bf16)b.w;
  return r;
}

// ---------------- fused prep: swizzled weight image + bf16 rows + hist -----
// Weight image: 6 panels [128 r][128 c]; row r byte b holds W[r][(b^((r&15)<<4))/2].
__global__ void prep_kernel(const float* __restrict__ We,
                            const float* __restrict__ Wn,
                            const float* __restrict__ Ws,
                            unsigned short* __restrict__ wimg,
                            const float* __restrict__ sx,
                            unsigned short* __restrict__ sb,
                            const float* __restrict__ rx,
                            unsigned short* __restrict__ rb,
                            int n8s, int n8r,
                            const int* __restrict__ dst,
                            int* __restrict__ counts, int E) {
  int i = blockIdx.x * 256 + threadIdx.x;
  if (i < 6 * 16384) {
    int panel = i >> 14;
    int r = (i >> 7) & 127;
    int csw = i & 127;
    int c_or = ((csw * 2) ^ ((r & 15) << 4)) >> 1;
    float f;
    if (panel < 3)      f = We[r * 384 + panel * 128 + c_or];
    else if (panel < 5) f = Wn[r * 256 + (panel - 3) * 128 + c_or];
    else                f = Ws[r * 128 + c_or];
    BF1 c; c.h = (__bf16)f;
    wimg[i] = c.s;
    return;
  }
  int j = i - 6 * 16384;
  if (j < n8s + n8r) {
    const float* in; unsigned short* out; int idx;
    if (j < n8s) { in = sx; out = sb; idx = j; }
    else         { in = rx; out = rb; idx = j - n8s; }
    float4 a = reinterpret_cast<const float4*>(in)[2 * idx];
    float4 b = reinterpret_cast<const float4*>(in)[2 * idx + 1];
    U16B r8; r8.v = cvt8(a, b);
    reinterpret_cast<uint4*>(out)[idx] = r8.u;
    return;
  }
  int e = j - n8s - n8r;
  if (e < E) atomicAdd(&counts[dst[e]], 1);
}

// ---------------- CSR build ----------------
__global__ void scan1_kernel(const int* __restrict__ counts, int* __restrict__ pre,
                             int* __restrict__ blockSums, int n) {
  __shared__ int sh[256];
  const int t = threadIdx.x;
  const int base = blockIdx.x * 1024 + t * 4;
  int c0 = (base + 0 < n) ? counts[base + 0] : 0;
  int c1 = (base + 1 < n) ? counts[base + 1] : 0;
  int c2 = (base + 2 < n) ? counts[base + 2] : 0;
  int c3 = (base + 3 < n) ? counts[base + 3] : 0;
  int tot = c0 + c1 + c2 + c3;
  sh[t] = tot;
  __syncthreads();
  #pragma unroll
  for (int off = 1; off < 256; off <<= 1) {
    int v = (t >= off) ? sh[t - off] : 0;
    __syncthreads();
    sh[t] += v;
    __syncthreads();
  }
  int excl = sh[t] - tot;
  if (base + 0 < n) pre[base + 0] = excl;
  if (base + 1 < n) pre[base + 1] = excl + c0;
  if (base + 2 < n) pre[base + 2] = excl + c0 + c1;
  if (base + 3 < n) pre[base + 3] = excl + c0 + c1 + c2;
  if (t == 255) blockSums[blockIdx.x] = sh[255];
}

__global__ void scan2_kernel(int* __restrict__ blockSums, int nb) {
  __shared__ int sh[512];
  const int t = threadIdx.x;
  int v = (t < nb) ? blockSums[t] : 0;
  sh[t] = v;
  __syncthreads();
  #pragma unroll
  for (int off = 1; off < 512; off <<= 1) {
    int u = (t >= off) ? sh[t - off] : 0;
    __syncthreads();
    sh[t] += u;
    __syncthreads();
  }
  if (t < nb) blockSums[t] = sh[t] - v;
}

__global__ void scan3_kernel(const int* __restrict__ pre, const int* __restrict__ blockSums,
                             int* __restrict__ offs, int* __restrict__ cursor, int n) {
  int i = blockIdx.x * 256 + threadIdx.x;
  if (i >= n) return;
  int o = pre[i] + blockSums[i >> 10];
  offs[i] = o;
  cursor[i] = o;
}

__global__ void scatter_kernel(const int* __restrict__ dst, int* __restrict__ cursor,
                               int* __restrict__ rank, int E) {
  int i = blockIdx.x * 256 + threadIdx.x;
  if (i < E) {
    int p = atomicAdd(&cursor[dst[i]], 1);
    rank[i] = p;
  }
}

// segment sum over CONTIGUOUS P rows [offs[r], offs[r]+counts[r])
__global__ __launch_bounds__(256) void agg_kernel(
    const unsigned short* __restrict__ P,
    const int* __restrict__ offs, const int* __restrict__ counts,
    unsigned short* __restrict__ aggr, int NR) {
  const int l = threadIdx.x & 31;
  const int g0 = (blockIdx.x * 256 + threadIdx.x) >> 5;
  if (g0 >= NR) return;
  int beg = offs[g0];
  int cnt = counts[g0];
  float s0 = 0.f, s1 = 0.f, s2 = 0.f, s3 = 0.f;
  const unsigned short* p = P + (size_t)beg * 128 + l * 4;
  for (int k = 0; k < cnt; ++k) {
    uint2 w = *reinterpret_cast<const uint2*>(p);
    p += 128;
    s0 += bfu2f(w.x & 0xffffu);
    s1 += bfu2f(w.x >> 16);
    s2 += bfu2f(w.y & 0xffffu);
    s3 += bfu2f(w.y >> 16);
  }
  BFPK a, b;
  a.h[0] = (__bf16)s0; a.h[1] = (__bf16)s1;
  b.h[0] = (__bf16)s2; b.h[1] = (__bf16)s3;
  uint2 o; o.x = a.u; o.y = b.u;
  *reinterpret_cast<uint2*>(aggr + (size_t)g0 * 128 + l * 4) = o;
}

// ---------------------------------------------------------------------------
// v10: bf16 s0/s1 features, fp32 s2. Single 32KB B buffer, 2-pass epilogue
// transpose overlaid in the same buffer. 512 thr / 8 waves / 128 rows.
// AGGR: 0=none, 2=pk bf16 atomics, 3=P row at prank[grow].
// ---------------------------------------------------------------------------
template <int KDIM, int AGGR>
__global__ __launch_bounds__(512, 6) void mlp_v10_kernel(
    const unsigned short* __restrict__ s0, const int* __restrict__ i0,
    const unsigned short* __restrict__ s1, const int* __restrict__ i1,
    const float* __restrict__ s2,
    const unsigned short* __restrict__ Wb,   // swizzled image, NSEG panels
    const float* __restrict__ bias, const float* __restrict__ gamma,
    const float* __restrict__ beta,
    const float* __restrict__ resid,
    float* __restrict__ outp,
    void* aggr, const int* __restrict__ aggr_idx,
    const int* __restrict__ prank,
    int M) {
  constexpr int NSEG = KDIM / 128;
  __shared__ __align__(16) unsigned short smem[16384];  // 32 KB single buffer

  const int tid = threadIdx.x;
  const int wid = tid >> 6;
  const int lane = tid & 63;
  const int l15 = lane & 15;
  const int q = lane >> 4;
  const int l31 = lane & 31;
  const int rhalf = lane >> 5;
  const int wrow = blockIdx.x * 128 + wid * 16;
  const int xm = l15 << 3;   // ushort-unit XOR for 4-bit row swizzle

  int rr = wrow + l15;
  if (rr >= M) rr = M - 1;  // clamp tail; stores masked later
  const unsigned short* p0 = s0 + (size_t)(i0 ? i0[rr] : rr) * 128;
  const unsigned short* p1 = nullptr;
  const float* p2 = nullptr;
  if constexpr (KDIM >= 256) p1 = s1 + (size_t)(i1 ? i1[rr] : rr) * 128;
  if constexpr (KDIM >= 384) p2 = s2 + (size_t)rr * 128;

  auto stageB = [&](int seg) {
    const unsigned short* g = Wb + seg * 16384 + wid * 2048 + lane * 8;
    unsigned short* l = &smem[wid * 2048];
    #pragma unroll
    for (int u = 0; u < 4; ++u) {
      __builtin_amdgcn_global_load_lds(
          (const __attribute__((address_space(1))) unsigned int*)(g + u * 512),
          (__attribute__((address_space(3))) unsigned int*)(l + u * 512),
          16, 0, 0);
    }
  };

  U16B Ac[4], An[4];
  auto loadA = [&](int seg, U16B (&dst)[4]) {
    #pragma unroll
    for (int k4 = 0; k4 < 4; ++k4) {
      const int kof = k4 * 32 + q * 8;
      if (seg == 0) {
        dst[k4].u = *reinterpret_cast<const uint4*>(p0 + kof);
      } else if (seg == 1) {
        dst[k4].u = *reinterpret_cast<const uint4*>(p1 + kof);
      } else {
        const float4* p = reinterpret_cast<const float4*>(p2 + kof);
        dst[k4].v = cvt8(p[0], p[1]);
      }
    }
  };

  f32x4 acc[8] = {};

  stageB(0);
  loadA(0, Ac);
  __syncthreads();                       // B0 + A0 landed

  #pragma unroll
  for (int seg = 0; seg < NSEG; ++seg) {
    if (seg + 1 < NSEG) loadA(seg + 1, An);   // gathers in flight over MFMA
    #pragma unroll
    for (int k4 = 0; k4 < 4; ++k4) {
      #pragma unroll
      for (int n = 0; n < 8; ++n) {
        U16B b;
        b.u = *reinterpret_cast<const uint4*>(
            &smem[(n * 16 + l15) * 128 + ((k4 * 32 + q * 8) ^ xm)]);
        acc[n] = __builtin_amdgcn_mfma_f32_16x16x32_bf16(Ac[k4].v, b.v, acc[n], 0, 0, 0);
      }
    }
    __syncthreads();                     // all reads of the buffer done
    if (seg + 1 < NSEG) {
      stageB(seg + 1);
      __syncthreads();                   // next panel staged
      #pragma unroll
      for (int k4 = 0; k4 < 4; ++k4) Ac[k4] = An[k4];
    }
  }
  // loop's final post-mfma barrier protects the overlay below

  // ---- epilogue: bias, silu^2, LN in acc; 2-pass per-wave transpose ----
  float bia[8];
  #pragma unroll
  for (int n = 0; n < 8; ++n) bia[n] = bias[n * 16 + l15];

  float sum[4] = {0.f, 0.f, 0.f, 0.f};
  float ssq[4] = {0.f, 0.f, 0.f, 0.f};
  #pragma unroll
  for (int n = 0; n < 8; ++n) {
    #pragma unroll
    for (int j = 0; j < 4; ++j) {
      float t = silu_f(silu_f(acc[n][j] + bia[n]));
      acc[n][j] = t;
      sum[j] += t;
      ssq[j] += t * t;
    }
  }
  #pragma unroll
  for (int off = 1; off < 16; off <<= 1) {
    #pragma unroll
    for (int j = 0; j < 4; ++j) {
      sum[j] += __shfl_xor(sum[j], off);
      ssq[j] += __shfl_xor(ssq[j], off);
    }
  }
  float mu[4], rs[4];
  #pragma unroll
  for (int j = 0; j < 4; ++j) {
    mu[j] = sum[j] * (1.0f / 128.0f);
    float var = ssq[j] * (1.0f / 128.0f) - mu[j] * mu[j];
    rs[j] = rsqrtf(var + 1e-5f);
  }
  float gam[8], bet[8];
  #pragma unroll
  for (int n = 0; n < 8; ++n) {
    gam[n] = gamma[n * 16 + l15];
    bet[n] = beta[n * 16 + l15];
  }

  unsigned short* yw = &smem[wid * 2048];  // per-wave 2048-ushort slice

  #pragma unroll
  for (int h = 0; h < 2; ++h) {
    if (h == 1) {
      asm volatile("s_waitcnt lgkmcnt(0)" ::: "memory");  // WAR: pass-0 reads done
    }
    // write: lanes whose rows fall in [8h, 8h+8) -> q in {2h, 2h+1}
    if ((q >> 1) == h) {
      #pragma unroll
      for (int n = 0; n < 8; ++n) {
        #pragma unroll
        for (int j = 0; j < 4; ++j) {
          float y = (acc[n][j] - mu[j]) * rs[j] * gam[n] + bet[n];
          BF1 c; c.h = (__bf16)y;
          yw[((q & 1) * 4 + j) * 132 + n * 16 + l15] = c.s;
        }
      }
    }
    asm volatile("s_waitcnt lgkmcnt(0)" ::: "memory");

    #pragma unroll
    for (int s = 0; s < 4; ++s) {
      int row8 = 2 * s + rhalf;            // 0..7 within this half
      int grow = wrow + 8 * h + row8;
      uint2 w = *reinterpret_cast<const uint2*>(&yw[row8 * 132 + l31 * 4]);
      if (grow < M) {
        const f32x4 r4 = *reinterpret_cast<const f32x4*>(resid + (size_t)grow * 128 + l31 * 4);
        f32x4 o4;
        o4.x = r4.x + bfu2f(w.x & 0xffffu);
        o4.y = r4.y + bfu2f(w.x >> 16);
        o4.z = r4.z + bfu2f(w.y & 0xffffu);
        o4.w = r4.w + bfu2f(w.y >> 16);
        __builtin_nontemporal_store(o4, reinterpret_cast<f32x4*>(outp + (size_t)grow * 128 + l31 * 4));
        if constexpr (AGGR == 3) {
          int prow = prank[grow];
          *reinterpret_cast<uint2*>((unsigned short*)aggr + (size_t)prow * 128 + l31 * 4) = w;
        } else if constexpr (AGGR == 2) {
          int idx = aggr_idx[grow];
          unsigned short* ar = (unsigned short*)aggr + (size_t)idx * 128 + l31 * 4;
          asm volatile("global_atomic_pk_add_bf16 %0, %1, off" :: "v"(ar), "v"(w.x) : "memory");
          asm volatile("global_atomic_pk_add_bf16 %0, %1, off" :: "v"(ar + 2), "v"(w.y) : "memory");
        }
      }
    }
  }
}

// ---------------------------------------------------------------------------
// fallback kernel (fp32 features, fp32 atomics) for small-ws tier.
// ---------------------------------------------------------------------------
template <int KDIM>
__global__ __launch_bounds__(512, 4) void mlp_fb_kernel(
    const float* __restrict__ s0, const int* __restrict__ i0,
    const float* __restrict__ s1, const int* __restrict__ i1,
    const float* __restrict__ s2,
    const unsigned short* __restrict__ Wb,
    const float* __restrict__ bias, const float* __restrict__ gamma,
    const float* __restrict__ beta,
    const float* __restrict__ resid,
    float* __restrict__ outp,
    float* aggr, const int* __restrict__ aggr_idx,
    int M) {
  constexpr int NSEG = KDIM / 128;
  __shared__ __align__(16) unsigned short smem[2][16384];
  const int tid = threadIdx.x;
  const int wid = tid >> 6;
  const int lane = tid & 63;
  const int l15 = lane & 15;
  const int q = lane >> 4;
  const int l31 = lane & 31;
  const int rhalf = lane >> 5;
  const int wrow = blockIdx.x * 128 + wid * 16;
  const int xm = l15 << 3;

  int rr = wrow + l15;
  if (rr >= M) rr = M - 1;
  const float* p0 = s0 + (size_t)(i0 ? i0[rr] : rr) * 128;
  const float* p1 = (KDIM >= 256) ? (s1 + (size_t)(i1 ? i1[rr] : rr) * 128) : nullptr;
  const float* p2 = (KDIM >= 384) ? (s2 + (size_t)rr * 128) : nullptr;

  auto stageB = [&](int seg, int buf) {
    const unsigned short* g = Wb + seg * 16384 + wid * 2048 + lane * 8;
    unsigned short* l = &smem[buf][wid * 2048];
    #pragma unroll
    for (int u = 0; u < 4; ++u) {
      __builtin_amdgcn_global_load_lds(
          (const __attribute__((address_space(1))) unsigned int*)(g + u * 512),
          (__attribute__((address_space(3))) unsigned int*)(l + u * 512),
          16, 0, 0);
    }
  };

  stageB(0, 0);
  f32x4 acc[8] = {};
  __syncthreads();
  int cur = 0;
  #pragma unroll
  for (int seg = 0; seg < NSEG; ++seg) {
    if (seg + 1 < NSEG) stageB(seg + 1, cur ^ 1);
    const float* base = (seg == 0) ? p0 : ((seg == 1) ? p1 : p2);
    #pragma unroll
    for (int k4 = 0; k4 < 4; ++k4) {
      const float4* pp = reinterpret_cast<const float4*>(base + k4 * 32 + q * 8);
      U16B a; a.v = cvt8(pp[0], pp[1]);
      #pragma unroll
      for (int n = 0; n < 8; ++n) {
        U16B b;
        b.u = *reinterpret_cast<const uint4*>(
            &smem[cur][(n * 16 + l15) * 128 + ((k4 * 32 + q * 8) ^ xm)]);
        acc[n] = __builtin_amdgcn_mfma_f32_16x16x32_bf16(a.v, b.v, acc[n], 0, 0, 0);
      }
    }
    __syncthreads();
    if (seg + 1 < NSEG) cur ^= 1;
  }

  unsigned short* yw = &smem[0][0] + wid * (16 * 132);
  float bia[8];
  #pragma unroll
  for (int n = 0; n < 8; ++n) bia[n] = bias[n * 16 + l15];
  float sum[4] = {0.f, 0.f, 0.f, 0.f}, ssq[4] = {0.f, 0.f, 0.f, 0.f};
  #pragma unroll
  for (int n = 0; n < 8; ++n)
    #pragma unroll
    for (int j = 0; j < 4; ++j) {
      float t = silu_f(silu_f(acc[n][j] + bia[n]));
      acc[n][j] = t; sum[j] += t; ssq[j] += t * t;
    }
  #pragma unroll
  for (int off = 1; off < 16; off <<= 1)
    #pragma unroll
    for (int j = 0; j < 4; ++j) {
      sum[j] += __shfl_xor(sum[j], off);
      ssq[j] += __shfl_xor(ssq[j], off);
    }
  float mu[4], rs[4];
  #pragma unroll
  for (int j = 0; j < 4; ++j) {
    mu[j] = sum[j] * (1.0f / 128.0f);
    float var = ssq[j] * (1.0f / 128.0f) - mu[j] * mu[j];
    rs[j] = rsqrtf(var + 1e-5f);
  }
  float gam[8], bet[8];
  #pragma unroll
  for (int n = 0; n < 8; ++n) { gam[n] = gamma[n * 16 + l15]; bet[n] = beta[n * 16 + l15]; }
  #pragma unroll
  for (int n = 0; n < 8; ++n)
    #pragma unroll
    for (int j = 0; j < 4; ++j) {
      float y = (acc[n][j] - mu[j]) * rs[j] * gam[n] + bet[n];
      BF1 c; c.h = (__bf16)y;
      yw[(q * 4 + j) * 132 + n * 16 + l15] = c.s;
    }
  asm volatile("s_waitcnt lgkmcnt(0)" ::: "memory");
  #pragma unroll
  for (int s = 0; s < 8; ++s) {
    int row16 = 2 * s + rhalf;
    int grow = wrow + row16;
    uint2 w = *reinterpret_cast<const uint2*>(&yw[row16 * 132 + l31 * 4]);
    if (grow < M) {
      const f32x4 r4 = *reinterpret_cast<const f32x4*>(resid + (size_t)grow * 128 + l31 * 4);
      f32x4 o4;
      o4.x = r4.x + bfu2f(w.x & 0xffffu);
      o4.y = r4.y + bfu2f(w.x >> 16);
      o4.z = r4.z + bfu2f(w.y & 0xffffu);
      o4.w = r4.w + bfu2f(w.y >> 16);
      __builtin_nontemporal_store(o4, reinterpret_cast<f32x4*>(outp + (size_t)grow * 128 + l31 * 4));
      if (aggr) {
        int idx = aggr_idx[grow];
        float* ar = aggr + (size_t)idx * 128 + l31 * 4;
        atomicAdd(ar + 0, bfu2f(w.x & 0xffffu));
        atomicAdd(ar + 1, bfu2f(w.x >> 16));
        atomicAdd(ar + 2, bfu2f(w.y & 0xffffu));
        atomicAdd(ar + 3, bfu2f(w.y >> 16));
      }
    }
  }
}

extern "C" void kernel_launch(void* const* d_in, const int* in_sizes, int n_in,
                              void* d_out, int out_size, void* d_ws, size_t ws_size,
                              hipStream_t stream) {
  const float* sender_x   = (const float*)d_in[0];
  const float* receiver_x = (const float*)d_in[1];
  const int*   edge_index = (const int*)d_in[2];
  const float* edge_attr  = (const float*)d_in[3];
  const float* We  = (const float*)d_in[4];
  const float* be  = (const float*)d_in[5];
  const float* ge  = (const float*)d_in[6];
  const float* bbe = (const float*)d_in[7];
  const float* Wn  = (const float*)d_in[8];
  const float* bn  = (const float*)d_in[9];
  const float* gn  = (const float*)d_in[10];
  const float* bbn = (const float*)d_in[11];
  const float* Ws  = (const float*)d_in[12];
  const float* bs  = (const float*)d_in[13];
  const float* gs  = (const float*)d_in[14];
  const float* bbs = (const float*)d_in[15];

  const int D  = 128;
  const int NS = in_sizes[0] / D;
  const int NR = in_sizes[1] / D;
  const int E  = in_sizes[2] / 2;

  const int* src = edge_index;
  const int* dst = edge_index + E;

  float* out          = (float*)d_out;
  float* sender_out   = out;
  float* receiver_out = out + (size_t)NS * D;
  float* edge_out     = out + (size_t)(NS + NR) * D;

  const size_t welems = 6 * 16384;
  unsigned short* We_b = (unsigned short*)d_ws;          // panels 0..2
  unsigned short* Wn_b = We_b + 3 * 16384;               // panels 3..4
  unsigned short* Ws_b = We_b + 5 * 16384;               // panel 5
  unsigned short* sender_b   = We_b + welems;
  unsigned short* receiver_b = sender_b + (size_t)NS * D;
  unsigned short* aggr_b     = receiver_b + (size_t)NR * D;
  unsigned short* P_b        = aggr_b + (size_t)NR * D;
  int* counts    = (int*)(P_b + (size_t)E * D);
  int* pre       = counts + NR;
  int* offs      = pre + NR;
  int* cursor    = offs + NR;
  int* blockSums = cursor + NR;
  int* rank      = blockSums + 512;

  const int nScanBlocks = (NR + 1023) / 1024;
  const size_t needCSR = 2 * (welems + (size_t)(NS + 2 * NR) * D + (size_t)E * D)
                       + 4 * (4 * (size_t)NR + 512 + (size_t)E);
  const size_t needA = (welems + (size_t)(NS + 2 * NR) * D) * 2;

  int tier;
  if (ws_size >= needCSR && nScanBlocks <= 512) tier = 0;
  else if (ws_size >= needA) tier = 1;
  else tier = 2;

  const int gridE = (E + 127) / 128;
  const int gridR = (NR + 127) / 128;
  const int gridS = (NS + 127) / 128;
  const int n8s = NS * D / 8, n8r = NR * D / 8;

  if (tier == 0) {
    (void)hipMemsetAsync(counts, 0, (size_t)NR * 4, stream);
    // fused prep: weight image + bf16 rows + dst histogram
    const int prepItems = (int)welems + n8s + n8r + E;
    prep_kernel<<<(prepItems + 255) / 256, 256, 0, stream>>>(
        We, Wn, Ws, We_b, sender_x, sender_b, receiver_x, receiver_b,
        n8s, n8r, dst, counts, E);

    scan1_kernel<<<nScanBlocks, 256, 0, stream>>>(counts, pre, blockSums, NR);
    scan2_kernel<<<1, 512, 0, stream>>>(blockSums, nScanBlocks);
    scan3_kernel<<<(NR + 255) / 256, 256, 0, stream>>>(pre, blockSums, offs, cursor, NR);
    scatter_kernel<<<(E + 255) / 256, 256, 0, stream>>>(dst, cursor, rank, E);

    mlp_v10_kernel<384, 3><<<gridE, 512, 0, stream>>>(
        sender_b, src, receiver_b, dst, edge_attr,
        We_b, be, ge, bbe, edge_attr, edge_out, P_b, nullptr, rank, E);

    agg_kernel<<<(NR + 7) / 8, 256, 0, stream>>>(P_b, offs, counts, aggr_b, NR);

    mlp_v10_kernel<256, 0><<<gridR, 512, 0, stream>>>(
        receiver_b, nullptr, aggr_b, nullptr, nullptr,
        Wn_b, bn, gn, bbn, receiver_x, receiver_out, nullptr, nullptr, nullptr, NR);

    mlp_v10_kernel<128, 0><<<gridS, 512, 0, stream>>>(
        sender_b, nullptr, nullptr, nullptr, nullptr,
        Ws_b, bs, gs, bbs, sender_x, sender_out, nullptr, nullptr, nullptr, NS);
  } else if (tier == 1) {
    const int prepItems = (int)welems + n8s + n8r;
    prep_kernel<<<(prepItems + 255) / 256, 256, 0, stream>>>(
        We, Wn, Ws, We_b, sender_x, sender_b, receiver_x, receiver_b,
        n8s, n8r, nullptr, nullptr, 0);
    (void)hipMemsetAsync(aggr_b, 0, (size_t)NR * D * 2, stream);

    mlp_v10_kernel<384, 2><<<gridE, 512, 0, stream>>>(
        sender_b, src, receiver_b, dst, edge_attr,
        We_b, be, ge, bbe, edge_attr, edge_out, aggr_b, dst, nullptr, E);

    mlp_v10_kernel<256, 0><<<gridR, 512, 0, stream>>>(
        receiver_b, nullptr, aggr_b, nullptr, nullptr,
        Wn_b, bn, gn, bbn, receiver_x, receiver_out, nullptr, nullptr, nullptr, NR);

    mlp_v10_kernel<128, 0><<<gridS, 512, 0, stream>>>(
        sender_b, nullptr, nullptr, nullptr, nullptr,
        Ws_b, bs, gs, bbs, sender_x, sender_out, nullptr, nullptr, nullptr, NS);
  } else {
    prep_kernel<<<(int)((welems + 255) / 256), 256, 0, stream>>>(
        We, Wn, Ws, We_b, nullptr, nullptr, nullptr, nullptr, 0, 0,
        nullptr, nullptr, 0);
    (void)hipMemsetAsync(receiver_out, 0, (size_t)NR * D * sizeof(float), stream);

    mlp_fb_kernel<384><<<gridE, 512, 0, stream>>>(
        sender_x, src, receiver_x, dst, edge_attr,
        We_b, be, ge, bbe, edge_attr, edge_out, receiver_out, dst, E);

    mlp_fb_kernel<256><<<gridR, 512, 0, stream>>>(
        receiver_x, nullptr, receiver_out, nullptr, nullptr,
        Wn_b, bn, gn, bbn, receiver_x, receiver_out, nullptr, nullptr, NR);

    mlp_fb_kernel<128><<<gridS, 512, 0, stream>>>(
        sender_x, nullptr, nullptr, nullptr, nullptr,
        Ws_b, bs, gs, bbs, sender_x, sender_out, nullptr, nullptr, NS);
  }
}